// Round 12
// baseline (154.628 us; speedup 1.0000x reference)
//
#include <hip/hip_runtime.h>
#include <hip/hip_cooperative_groups.h>

namespace cg = cooperative_groups;

#define NCLS    20
#define NB      8
#define MAXDET  300
#define NEGV    (-1e9f)
#define NEGH    (-5e8f)
#define BLKN    512
#define BLKC    1024
#define KTARGET 896
#define KMAX    1024
#define NBIN    256
#define NSLICE  32
#define CSTR    16        // global counter stride (u32s) -> one 64B line per counter

// exact: RN_f32(inter/den) > 0.5  <=>  (double)inter > T_MID * (double)den   (den>0)
// T_MID = 0.5 + 2^-25 exactly representable; 25-bit x 24-bit product exact in f64.
#define T_MID   0x1.000001p-1

typedef unsigned long long u64;
typedef unsigned int u32;

__device__ __forceinline__ u64 packkey(float s, int j) {
    // valid scores are > 0.05 (positive): bits^0x80000000 order-preserving; ~j -> lower idx wins
    return ((u64)(__float_as_uint(s) ^ 0x80000000u) << 32) | (u32)(~(u32)j);
}
__device__ __forceinline__ u64 wredmax64(u64 k) {
#pragma unroll
    for (int off = 32; off > 0; off >>= 1) {
        u64 o = __shfl_xor(k, off);
        if (o > k) k = o;
    }
    return k;
}
__device__ __forceinline__ int binfull(float s) {
    int full = (int)(s * 262144.0f);          // 2^18 fine resolution, monotone
    return full > 262143 ? 262143 : full;
}
__device__ __forceinline__ int bin256(float s) { return binfull(s) >> 10; }

// ---------------- Fused pre-kernel (cooperative): zero + hist + thresholds + collect ----------------
__global__ __launch_bounds__(BLKN, 1) void fused_pre_kernel(
    const float* __restrict__ cls,
    u32* __restrict__ hist_sum_g,      // [NP*NBIN]; contiguous with cntHi,cntLo for phase-0 zeroing
    u32* __restrict__ cntHi, u32* __restrict__ cntLo,
    u64* __restrict__ keys_g,
    int4* __restrict__ meta_g,         // per pair: {thr, hiCnt, total, loTot}
    int n)
{
    cg::grid_group grid = cg::this_grid();
    const int b = blockIdx.x & 7;            // same-image blocks -> same XCD
    const int slice = blockIdx.x >> 3;       // 0..31
    const int tid = threadIdx.x;
    const int lane = tid & 63;
    const int wv = tid >> 6;

    __shared__ u32 lh[NCLS * NBIN];          // 20KB: this slice's histogram (stays live!)
    __shared__ u32 sumh[NCLS * NBIN];        // 20KB: per-image summed hist
    __shared__ int thrB[NCLS], cAs[NCLS], tots[NCLS], loTs[NCLS];
    __shared__ u32 lcHi[NCLS], lcLo[NCLS], baseHi[NCLS], baseLo[NCLS];

    // ---- phase 0: striped zero of hist_sum + counters (contiguous 46080 words) ----
    {
        const int ZW = NB * NCLS * NBIN + 2 * NB * NCLS * CSTR;   // 40960 + 5120
        for (int i = blockIdx.x * BLKN + tid; i < ZW; i += NB * NSLICE * BLKN) hist_sum_g[i] = 0;
    }
    for (int i = tid; i < NCLS * NBIN; i += BLKN) lh[i] = 0;
    __syncthreads();
    grid.sync();                              // zeros visible device-wide

    // ---- phase 1: per-slice hist in LDS, atomic merge into per-image sum ----
    const int F4 = (n * NCLS) >> 2;
    const int s0 = (int)(((long)slice * F4) >> 5);
    const int s1 = (int)(((long)(slice + 1) * F4) >> 5);
    const float4* p4 = (const float4*)(cls + (long)b * n * NCLS);
    for (int q = s0 + tid; q < s1; q += BLKN) {
        float4 v = p4[q];
        int f = q << 2;
        float ss[4] = {v.x, v.y, v.z, v.w};
#pragma unroll
        for (int e = 0; e < 4; ++e) {
            float sc = ss[e];
            if (sc > 0.05f) {                 // strict >, like reference
                u32 c = (u32)(f + e) % NCLS;
                atomicAdd(&lh[c * NBIN + bin256(sc)], 1u);
            }
        }
    }
    __syncthreads();
    for (int i = tid; i < NCLS * NBIN; i += BLKN) {
        u32 v = lh[i];
        if (v) atomicAdd(&hist_sum_g[(b * NCLS + (i >> 8)) * NBIN + (i & 255)], v);
    }
    grid.sync();                              // all merges complete

    // ---- phase 2a: thresholds from summed hist (suffix scan, 4 bins/lane, wave per class) ----
    for (int i = tid; i < NCLS * NBIN; i += BLKN) sumh[i] = hist_sum_g[b * (NCLS * NBIN) + i];
    __syncthreads();
    for (int c = wv; c < NCLS; c += 8) {
        u32 g0 = sumh[c * NBIN + 4 * lane],     g1 = sumh[c * NBIN + 4 * lane + 1],
            g2 = sumh[c * NBIN + 4 * lane + 2], g3 = sumh[c * NBIN + 4 * lane + 3];
        int acc = (int)(g0 + g1 + g2 + g3);
#pragma unroll
        for (int d = 1; d < 64; d <<= 1) { int o = __shfl_down(acc, d); if (lane + d < 64) acc += o; }
        int S0 = acc, S1 = S0 - (int)g0, S2 = S1 - (int)g1, S3 = S2 - (int)g2, S4 = S3 - (int)g3;
        if (lane == 0) { thrB[c] = -1; cAs[c] = 0; tots[c] = S0; loTs[c] = 0; }
        int bin = -1, ca = 0; u32 loT = 0;
        if      (S0 >= KTARGET && S1 < KTARGET) { bin = 4 * lane;     ca = S1; loT = g0; }
        else if (S1 >= KTARGET && S2 < KTARGET) { bin = 4 * lane + 1; ca = S2; loT = g1; }
        else if (S2 >= KTARGET && S3 < KTARGET) { bin = 4 * lane + 2; ca = S3; loT = g2; }
        else if (S3 >= KTARGET && S4 < KTARGET) { bin = 4 * lane + 3; ca = S4; loT = g3; }
        if (bin >= 0) { thrB[c] = bin; cAs[c] = ca; loTs[c] = (int)loT; }
    }
    __syncthreads();

    // ---- phase 2b: own hi/lo counts straight from the still-live LDS hist ----
    for (int c = wv; c < NCLS; c += 8) {
        const int B = thrB[c];
        u32 h0 = lh[c * NBIN + 4 * lane],     h1 = lh[c * NBIN + 4 * lane + 1],
            h2 = lh[c * NBIN + 4 * lane + 2], h3 = lh[c * NBIN + 4 * lane + 3];
        const int bin0 = 4 * lane;
        u32 part = 0;
        if (bin0     > B) part += h0;
        if (bin0 + 1 > B) part += h1;
        if (bin0 + 2 > B) part += h2;
        if (bin0 + 3 > B) part += h3;
        u32 lov = 0;
        if (B >= 0 && (B >> 2) == lane) lov = (B & 3) == 0 ? h0 : (B & 3) == 1 ? h1 : (B & 3) == 2 ? h2 : h3;
#pragma unroll
        for (int off = 32; off > 0; off >>= 1) {
            part += __shfl_xor(part, off);
            lov  += __shfl_xor(lov,  off);
        }
        if (lane == 0) { lcHi[c] = part; lcLo[c] = lov; }
    }
    __syncthreads();

    // meta publish (one block per image; identical values everywhere)
    if (slice == 0 && tid < NCLS) {
        const int hiCnt = (thrB[tid] < 0) ? tots[tid] : cAs[tid];   // B=-1: everything goes hi
        meta_g[b * NCLS + tid] = make_int4(thrB[tid], hiCnt, tots[tid], loTs[tid]);
    }

    // bulk reservation: ONE global atomic per (class, block) on padded counters
    if (tid < NCLS) {
        const int pair = b * NCLS + tid;
        u32 h = lcHi[tid], l = lcLo[tid];
        baseHi[tid] = h ? atomicAdd(&cntHi[pair * CSTR], h) : 0u;
        baseLo[tid] = l ? atomicAdd(&cntLo[pair * CSTR], l) : 0u;
        lcHi[tid] = 0; lcLo[tid] = 0;
    }
    __syncthreads();

    // ---- phase 2c: write pass over own cls slice (L2-warm re-read) ----
    for (int q = s0 + tid; q < s1; q += BLKN) {
        float4 v = p4[q];
        int f = q << 2;
        float ss[4] = {v.x, v.y, v.z, v.w};
#pragma unroll
        for (int e = 0; e < 4; ++e) {
            float sc = ss[e];
            if (sc > 0.05f) {
                u32 fe = (u32)(f + e);
                u32 c = fe % NCLS;
                int row = (int)(fe / NCLS);
                int bn = bin256(sc), B = thrB[c];
                const int pair = b * NCLS + (int)c;
                if (bn > B) {
                    u32 r = atomicAdd(&lcHi[c], 1u);
                    keys_g[(long)pair * KMAX + baseHi[c] + r] = packkey(sc, row);
                } else if (bn == B) {
                    u32 r = atomicAdd(&lcLo[c], 1u);
                    int pos = KMAX - 1 - (int)(baseLo[c] + r);
                    if (pos >= cAs[c]) keys_g[(long)pair * KMAX + pos] = packkey(sc, row);
                }
            }
        }
    }
}

// ---------------- hybrid bitonic helpers ----------------
__device__ __forceinline__ u64 cmb(u64 e, u64 p, int i, int jj, int k2) {
    bool up = ((i & k2) == 0);
    bool low = ((i & jj) == 0);
    return (up == low) ? (e > p ? e : p) : (e < p ? e : p);
}
// 1024 u64, 1/thread, 1024 threads: jj<=32 via shfl (no barrier), jj>=64 ping-pong LDS.
__device__ __forceinline__ void sort1024_1(u64& e, int tid, u64* bufA, u64* bufB) {
    int parity = 0;
    for (int k2 = 2; k2 <= KMAX; k2 <<= 1) {
        for (int jj = k2 >> 1; jj > 0; jj >>= 1) {
            if (jj >= 64) {
                u64* buf = parity ? bufB : bufA; parity ^= 1;
                buf[tid] = e;
                __syncthreads();
                u64 p = buf[tid ^ jj];
                e = cmb(e, p, tid, jj, k2);
            } else {
                u64 p = __shfl_xor(e, jj);
                e = cmb(e, p, tid, jj, k2);
            }
        }
    }
    __syncthreads();
    bufA[tid] = e;                 // final sorted array -> bufA
    __syncthreads();
}

// ---------------- Kernel C: per-pair sort + greedy (reference-exact, round-8 proven) ----------------
template<bool PRE>
__global__ __launch_bounds__(BLKC, 1) void nms_final_kernel(
    const float4* __restrict__ boxes,
    const float*  __restrict__ cls,
    const u64* __restrict__ keys_g,
    const int4* __restrict__ meta_g,
    float* __restrict__ sel_ws, int* __restrict__ idx_ws, int n)
{
    const int b = blockIdx.x & 7;
    const int c = blockIdx.x >> 3;
    const int pair = b * NCLS + c;
    const int tid = threadIdx.x;
    const int lane = tid & 63;
    const int wv = tid >> 6;                 // 0..15

    const float4* bb = boxes + (long)b * n;
    const float* srow = cls + (long)b * n * NCLS + c;   // strided (fallback rounds only)
    float* selp = sel_ws + pair * MAXDET;
    int*   idxp = idx_ws + pair * MAXDET;

    __shared__ u64    keysA[KMAX], keysB[KMAX];   // 16KB
    __shared__ float4 cbox[KMAX];                 // 16KB: candidate boxes (preloaded)
    __shared__ float4 aBox[MAXDET];               // 4.8KB: accepted boxes
    __shared__ u32    hist256[NBIN];
    __shared__ u32    kb0[64], kb1[64], psupm[2];
    __shared__ u64    wl[16];
    __shared__ int    ctrl[8];   // 0:B 1:cumAbove 2:cumTotal 3:cntLo 4:cntHi 5:k
    __shared__ u64    ubk;

    if (tid == 0) { ubk = ~0ull; ctrl[5] = 0; }
    if (tid < 64) { kb0[tid] = 0; kb1[tid] = 0; }
    if (tid < 2)  psupm[tid] = 0;
    bool first = true;
    __syncthreads();

    while (true) {
        const u64 UB = ubk;
        u64 e = 0;
        int trusted, cumTotal;

        if (PRE && first) {
            const int4 m = meta_g[pair];     // {thr, hiCnt, total, loTot}
            cumTotal = m.z;
            if (cumTotal == 0) break;
            const int hi = m.y;
            const int lo = m.w;
            const bool dropped = lo > (KMAX - hi);
            trusted = dropped ? hi : (hi + lo);
            const int lo_start = dropped ? hi : (KMAX - lo);   // dropped: cells >= hi all written
            if (tid < hi || tid >= lo_start) e = keys_g[(long)pair * KMAX + tid];
            if (trusted > 0) {
                sort1024_1(e, tid, keysA, keysB);
            } else {
                // boundary overflow w/ empty hi region: single best key < UB (progress)
                u64 lb = 0;
                for (int j = tid; j < n; j += BLKC) {
                    float sc = srow[(long)j * NCLS];
                    if (sc > 0.05f) { u64 ky = packkey(sc, j); if (ky < UB && ky > lb) lb = ky; }
                }
                lb = wredmax64(lb);
                if (lane == 0) wl[wv] = lb;
                __syncthreads();
                if (tid == 0) { u64 bk = 0; for (int w = 0; w < 16; ++w) if (wl[w] > bk) bk = wl[w]; keysA[0] = bk; }
                trusted = 1;
                __syncthreads();
            }
        } else {
            // ---- fallback rounds: full strided rescan (rare; correctness path) ----
            if (tid < NBIN) hist256[tid] = 0;
            keysA[tid] = 0;
            if (tid > 0 && tid < 5) ctrl[tid] = 0;
            if (tid == 0) ctrl[0] = -1;
            __syncthreads();
            for (int j = tid; j < n; j += BLKC) {
                float sc = srow[(long)j * NCLS];
                if (sc > 0.05f) { u64 ky = packkey(sc, j); if (ky < UB) atomicAdd(&hist256[bin256(sc)], 1u); }
            }
            __syncthreads();
            if (wv == 0) {
                u32 h0 = hist256[4 * lane], h1 = hist256[4 * lane + 1],
                    h2 = hist256[4 * lane + 2], h3 = hist256[4 * lane + 3];
                int acc = (int)(h0 + h1 + h2 + h3);
#pragma unroll
                for (int d = 1; d < 64; d <<= 1) { int o = __shfl_down(acc, d); if (lane + d < 64) acc += o; }
                int S0 = acc, S1 = S0 - (int)h0, S2 = S1 - (int)h1, S3 = S2 - (int)h2, S4 = S3 - (int)h3;
                if (lane == 0) { ctrl[0] = -1; ctrl[1] = 0; ctrl[2] = S0; }
                int bin = -1, ca = 0;
                if      (S0 >= KTARGET && S1 < KTARGET) { bin = 4 * lane;     ca = S1; }
                else if (S1 >= KTARGET && S2 < KTARGET) { bin = 4 * lane + 1; ca = S2; }
                else if (S2 >= KTARGET && S3 < KTARGET) { bin = 4 * lane + 2; ca = S3; }
                else if (S3 >= KTARGET && S4 < KTARGET) { bin = 4 * lane + 3; ca = S4; }
                if (bin >= 0) { ctrl[0] = bin; ctrl[1] = ca; }
            }
            __syncthreads();
            cumTotal = ctrl[2];
            if (cumTotal == 0) break;
            const int cumAbove = ctrl[1];
            const int B = ctrl[0];
            for (int j = tid; j < n; j += BLKC) {
                float sc = srow[(long)j * NCLS];
                if (sc > 0.05f) {
                    u64 ky = packkey(sc, j);
                    if (ky < UB) {
                        int bn = bin256(sc);
                        if (bn > B) { int sl = atomicAdd(&ctrl[4], 1); if (sl < KMAX) keysA[sl] = ky; }
                        else if (bn == B) {
                            int p = atomicAdd(&ctrl[3], 1);
                            int pos = KMAX - 1 - p;
                            if (pos >= cumAbove) keysA[pos] = ky;
                        }
                    }
                }
            }
            __syncthreads();
            const int cLo = ctrl[3], cHi = ctrl[4];
            const bool dropped = (cHi + cLo) > KMAX;
            trusted = dropped ? cHi : (cHi + cLo);
            if (trusted > 0) {
                e = keysA[tid];
                __syncthreads();
                sort1024_1(e, tid, keysA, keysB);
            } else {
                u64 lb = 0;
                for (int j = tid; j < n; j += BLKC) {
                    float sc = srow[(long)j * NCLS];
                    if (sc > 0.05f) { u64 ky = packkey(sc, j); if (ky < UB && ky > lb) lb = ky; }
                }
                lb = wredmax64(lb);
                if (lane == 0) wl[wv] = lb;
                __syncthreads();
                if (tid == 0) { u64 bk = 0; for (int w = 0; w < 16; ++w) if (wl[w] > bk) bk = wl[w]; keysA[0] = bk; }
                trusted = 1;
                __syncthreads();
            }
        }

        // ---- preload ALL candidate boxes (one wide gather, off the per-chunk critical path) ----
        {
            u64 ky = (tid < trusted) ? keysA[tid] : 0;
            float4 bx = make_float4(0.f, 0.f, 0.f, 0.f);
            if (tid < trusted) bx = bb[(int)(~(u32)ky)];
            cbox[tid] = bx;
        }
        __syncthreads();

        // ---- greedy over sorted prefix: 2 barriers/chunk ----
        for (int base = 0; base < trusted; base += 64) {
            const int kcur = ctrl[5];        // uniform (after barrier)
            if (kcur >= MAXDET) break;
            const int ci = base + lane;
            const bool have = ci < trusted;
            const float4 pb = cbox[have ? ci : 0];
            const float par = (pb.z - pb.x) * (pb.w - pb.y);

            // (a) candidate vs prior accepted, split across 16 waves; float4 broadcast + exact f64 cmp
            bool sup = false;
            for (int a = wv; a < kcur; a += 16) {
                float4 ab = aBox[a];
                float am = (ab.z - ab.x) * (ab.w - ab.y);
                float ltx = fmaxf(ab.x, pb.x), lty = fmaxf(ab.y, pb.y);
                float rbx = fminf(ab.z, pb.z), rby = fminf(ab.w, pb.w);
                float wx = fmaxf(rbx - ltx, 0.0f), wy = fmaxf(rby - lty, 0.0f);
                float inter = wx * wy;
                float den = ((par + am) - inter) + 1e-9f;   // ref op order
                sup = sup || ((double)inter > T_MID * (double)den);
            }
            u64 bal = __ballot(sup && have);
            if (lane == 0 && bal) { atomicOr(&psupm[0], (u32)bal); atomicOr(&psupm[1], (u32)(bal >> 32)); }

            // (b) in-chunk kill matrix: killer=lane, victim m; 16 waves x 4 victims
#pragma unroll
            for (int r = 0; r < 4; ++r) {
                const int m = (r << 4) | wv;
                if (lane < m && (base + m) < trusted) {     // lane<m => lane has a real candidate
                    float4 vb = cbox[base + m];
                    float va = (vb.z - vb.x) * (vb.w - vb.y);
                    float ltx = fmaxf(pb.x, vb.x), lty = fmaxf(pb.y, vb.y);
                    float rbx = fminf(pb.z, vb.z), rby = fminf(pb.w, vb.w);
                    float wx = fmaxf(rbx - ltx, 0.0f), wy = fmaxf(rby - lty, 0.0f);
                    float inter = wx * wy;
                    float den = ((va + par) - inter) + 1e-9f;  // victim area first (ref order)
                    if ((double)inter > T_MID * (double)den) {
                        if (lane < 32) atomicOr(&kb0[m], 1u << lane);
                        else           atomicOr(&kb1[m], 1u << (lane - 32));
                    }
                }
            }
            __syncthreads();                 // bar 1

            // (c) wave 0: ballot fixpoint (== sequential greedy), accept, clear masks
            if (tid < 64) {
                const u64 kbm = ((u64)kb1[lane] << 32) | kb0[lane];
                const u64 ps  = ((u64)psupm[1] << 32) | psupm[0];
                const bool alive0 = have && !((ps >> lane) & 1);
                u64 accm = __ballot(alive0);
                for (int it = 0; it < 64; ++it) {
                    u64 nm = __ballot(alive0 && ((kbm & accm) == 0ull));
                    if (nm == accm) break;
                    accm = nm;
                }
                const bool a = (accm >> lane) & 1;
                const int rank = (int)__popcll(accm & ((1ull << lane) - 1ull));
                const int rem = MAXDET - kcur;
                if (a && rank < rem) {
                    const int slot = kcur + rank;
                    aBox[slot] = pb;
                    const u64 ky = keysA[ci];
                    selp[slot] = __uint_as_float((u32)(ky >> 32) ^ 0x80000000u);
                    idxp[slot] = (int)(~(u32)ky);
                }
                kb0[lane] = 0; kb1[lane] = 0;
                if (lane < 2) psupm[lane] = 0;
                if (lane == 0) {
                    const int cnt = (int)__popcll(accm);
                    ctrl[5] = kcur + (cnt < rem ? cnt : rem);
                }
            }
            __syncthreads();                 // bar 2
        }

        if (tid == 0) ubk = keysA[trusted - 1];
        first = false;
        __syncthreads();
        if (ctrl[5] >= MAXDET || cumTotal - trusted <= 0) break;
    }

    const int kfin = ctrl[5];
    for (int f = kfin + tid; f < MAXDET; f += BLKC) { selp[f] = NEGV; idxp[f] = 0; }
}

// ---------------- Kernel D: per-image global top-300 via 2-level select + gather ----------------
#define OFF_B3D (NB * MAXDET * 4)
#define OFF_SC  (OFF_B3D + NB * MAXDET * 16)
#define OFF_LAB (OFF_SC + NB * MAXDET)

__global__ __launch_bounds__(512, 1) void topk_kernel(
    const float4* __restrict__ boxes,
    const float*  __restrict__ b3d,
    const float*  __restrict__ sel_ws,
    const int*    __restrict__ idx_ws,
    float* __restrict__ out,
    int n)
{
    const int b = blockIdx.x;
    const int tid = threadIdx.x;
    const int lane = tid & 63;
    const int wv = tid >> 6;
    const int M = NCLS * MAXDET;              // 6000

    __shared__ u64  kall[NCLS * MAXDET];      // 48KB
    __shared__ u32  h1[512];
    __shared__ u64  keysA[512], keysB[512];
    __shared__ int  wts[8], ews[8];
    __shared__ int  ctrl[8];
    __shared__ int  outA[MAXDET];

    const float* sp = sel_ws + b * M;
    for (int f = tid; f < M; f += 512) {
        float v = sp[f];
        kall[f] = (v > 0.05f) ? packkey(v, f) : 0ull;
    }
    h1[tid] = 0;
    keysA[tid] = 0;
    if (tid > 0 && tid < 8) ctrl[tid] = 0;
    if (tid == 0) { ctrl[0] = -1; ctrl[5] = -1; }
    __syncthreads();

    for (int f = tid; f < M; f += 512) {
        u64 k = kall[f];
        if (k) {
            float s = __uint_as_float((u32)(k >> 32) ^ 0x80000000u);
            atomicAdd(&h1[binfull(s) >> 9], 1u);
        }
    }
    __syncthreads();
    {
        const int h = (int)h1[tid];
        int acc = h;
#pragma unroll
        for (int d = 1; d < 64; d <<= 1) { int o = __shfl_down(acc, d); if (lane + d < 64) acc += o; }
        if (lane == 0) wts[wv] = acc;
        __syncthreads();
        if (tid < 8) { int e = 0; for (int w = tid + 1; w < 8; ++w) e += wts[w]; ews[tid] = e; }
        __syncthreads();
        const int S = acc + ews[wv];
        if (S >= MAXDET && (S - h) < MAXDET) { ctrl[0] = tid; ctrl[1] = S - h; }
        if (tid == 0) ctrl[2] = S;
    }
    __syncthreads();
    const int B1 = ctrl[0];
    const int cA1 = ctrl[1];

    h1[tid] = 0;
    __syncthreads();
    if (B1 >= 0) {
        for (int f = tid; f < M; f += 512) {
            u64 k = kall[f];
            if (k) {
                float s = __uint_as_float((u32)(k >> 32) ^ 0x80000000u);
                int full = binfull(s);
                if ((full >> 9) == B1) atomicAdd(&h1[full & 511], 1u);
            }
        }
    }
    __syncthreads();
    const int KT2 = MAXDET - cA1;
    {
        const int h = (int)h1[tid];
        int acc = h;
#pragma unroll
        for (int d = 1; d < 64; d <<= 1) { int o = __shfl_down(acc, d); if (lane + d < 64) acc += o; }
        if (lane == 0) wts[wv] = acc;
        __syncthreads();
        if (tid < 8) { int e = 0; for (int w = tid + 1; w < 8; ++w) e += wts[w]; ews[tid] = e; }
        __syncthreads();
        const int S = acc + ews[wv];
        if (B1 >= 0 && S >= KT2 && (S - h) < KT2) { ctrl[5] = tid; ctrl[6] = S - h; }
    }
    __syncthreads();
    const int B2 = ctrl[5];
    const int cA2 = ctrl[6];

    for (int f = tid; f < M; f += 512) {
        u64 k = kall[f];
        if (k) {
            float s = __uint_as_float((u32)(k >> 32) ^ 0x80000000u);
            int full = binfull(s);
            int bkt = full >> 9, sub = full & 511;
            bool hi = (B1 < 0) || (bkt > B1) || (bkt == B1 && sub > B2);
            bool lo = (B1 >= 0) && (bkt == B1) && (sub == B2);
            if (hi) { int slot = atomicAdd(&ctrl[3], 1); if (slot < 512) keysA[slot] = k; }
            else if (lo) { int p = atomicAdd(&ctrl[4], 1); int pos = 511 - p; if (pos >= cA1 + cA2) keysA[pos] = k; }
        }
    }
    __syncthreads();
    const bool dropped = (ctrl[3] + ctrl[4]) > 512;

    if (!dropped) {
        u64 e = keysA[tid];
        int parity = 0;
        for (int k2 = 2; k2 <= 512; k2 <<= 1) {
            for (int jj = k2 >> 1; jj > 0; jj >>= 1) {
                if (jj >= 64) {
                    u64* buf = parity ? keysB : keysA; parity ^= 1;
                    buf[tid] = e;
                    __syncthreads();
                    u64 p = buf[tid ^ jj];
                    e = cmb(e, p, tid, jj, k2);
                } else {
                    u64 p = __shfl_xor(e, jj);
                    e = cmb(e, p, tid, jj, k2);
                }
            }
        }
        __syncthreads();
        keysA[tid] = e;
        __syncthreads();
    } else {
        if (tid < 64) {
            int pos = 0;
            for (int k = 0; k < MAXDET; ++k) {
                u64 key = 0;
                if (lane < NCLS && pos < MAXDET) key = kall[lane * MAXDET + pos];
                u64 r = wredmax64(key);
                if (r != 0) {
                    u64 bal = __ballot(key == r);
                    int w = __ffsll((long long)bal) - 1;
                    if (lane == w) pos++;
                }
                if (lane == 0) keysA[k] = r;
            }
        }
        __syncthreads();
    }

    for (int k = tid; k < MAXDET; k += 512) {
        const u64 kk = keysA[k];
        const bool ok = kk != 0;
        const int flat = (int)(~(u32)kk);
        const float sc = __uint_as_float((u32)(kk >> 32) ^ 0x80000000u);
        const int a = ok ? idx_ws[b * M + flat] : -1;
        const int cc = flat / MAXDET;
        float4 bx = make_float4(-1.f, -1.f, -1.f, -1.f);
        if (ok) bx = boxes[(long)b * n + a];
        out[(long)b * MAXDET * 4 + k * 4 + 0] = bx.x;
        out[(long)b * MAXDET * 4 + k * 4 + 1] = bx.y;
        out[(long)b * MAXDET * 4 + k * 4 + 2] = bx.z;
        out[(long)b * MAXDET * 4 + k * 4 + 3] = bx.w;
        out[OFF_SC  + (long)b * MAXDET + k] = ok ? sc : -1.0f;
        out[OFF_LAB + (long)b * MAXDET + k] = ok ? (float)cc : -1.0f;
        outA[k] = a;
    }
    __syncthreads();
    for (int q = tid; q < MAXDET * 16; q += 512) {
        const int k = q >> 4;
        const int a = outA[k];
        out[OFF_B3D + (long)b * MAXDET * 16 + q] = (a >= 0) ? b3d[((long)b * n + a) * 16 + (q & 15)] : -1.0f;
    }
}

extern "C" void kernel_launch(void* const* d_in, const int* in_sizes, int n_in,
                              void* d_out, int out_size, void* d_ws, size_t ws_size,
                              hipStream_t stream)
{
    const float* boxes = (const float*)d_in[0];   // [8, N, 4]
    const float* b3d   = (const float*)d_in[1];   // [8, N, 16]
    const float* cls   = (const float*)d_in[2];   // [8, N, 20]
    float* out = (float*)d_out;

    int n = in_sizes[0] / (NB * 4);               // 49104
    const int NP = NB * NCLS;                     // 160

    const size_t sumB   = (size_t)NP * NBIN * sizeof(u32);                   // 160KB
    const size_t cntB   = (size_t)NP * CSTR * sizeof(u32);                   // 10KB each
    const size_t metaB  = (size_t)NP * sizeof(int4);                         // 2.5KB
    const size_t keysB_ = (size_t)NP * KMAX * sizeof(u64);                   // 1.25MB
    const size_t selB   = (size_t)NP * MAXDET * sizeof(float);

    char* p = (char*)d_ws;
    u32*  hist_sum_g = (u32*)p;            p += sumB;     // | contiguous zero region:
    u32*  cntHi      = (u32*)p;            p += cntB;     // | sum + cntHi + cntLo
    u32*  cntLo      = (u32*)p;            p += cntB;     // | = 46080 words
    int4* meta_g     = (int4*)p;           p += metaB;
    u64*  keys_g     = (u64*)p;            p += keysB_;
    float* sel_ws    = (float*)p;          p += selB;
    int*   idx_ws    = (int*)p;            p += selB;

    if (ws_size >= (size_t)(p - (char*)d_ws)) {
        void* kargs[] = { (void*)&cls, (void*)&hist_sum_g, (void*)&cntHi, (void*)&cntLo,
                          (void*)&keys_g, (void*)&meta_g, (void*)&n };
        hipLaunchCooperativeKernel((const void*)fused_pre_kernel,
                                   dim3(NB * NSLICE), dim3(BLKN), kargs, 0, stream);
        hipLaunchKernelGGL((nms_final_kernel<true>), dim3(NP), dim3(BLKC), 0, stream,
                           (const float4*)boxes, cls, keys_g, meta_g, sel_ws, idx_ws, n);
        hipLaunchKernelGGL(topk_kernel, dim3(NB), dim3(512), 0, stream,
                           (const float4*)boxes, b3d, sel_ws, idx_ws, out, n);
    } else {
        float* sel2 = (float*)d_ws;
        int*   idx2 = (int*)((char*)d_ws + selB);
        hipLaunchKernelGGL((nms_final_kernel<false>), dim3(NP), dim3(BLKC), 0, stream,
                           (const float4*)boxes, cls, nullptr, nullptr, sel2, idx2, n);
        hipLaunchKernelGGL(topk_kernel, dim3(NB), dim3(512), 0, stream,
                           (const float4*)boxes, b3d, sel2, idx2, out, n);
    }
}

// Round 13
// 97.471 us; speedup vs baseline: 1.5864x; 1.5864x over previous
//
#include <hip/hip_runtime.h>

#define NCLS    20
#define NB      8
#define MAXDET  300
#define NEGV    (-1e9f)
#define NEGH    (-5e8f)
#define BLKN    512
#define BLKC    1024
#define KTARGET 448
#define KMAX    512
#define NBIN    256
#define NSLICE  32
#define CSTR    16        // global counter stride (u32s) -> one 64B line per counter

// exact: RN_f32(inter/den) > 0.5  <=>  (double)inter > T_MID * (double)den   (den>0)
// T_MID = 0.5 + 2^-25 exactly representable; 25-bit x 24-bit product exact in f64.
#define T_MID   0x1.000001p-1

typedef unsigned long long u64;
typedef unsigned int u32;

__device__ __forceinline__ u64 packkey(float s, int j) {
    // valid scores are > 0.05 (positive): bits^0x80000000 order-preserving; ~j -> lower idx wins
    return ((u64)(__float_as_uint(s) ^ 0x80000000u) << 32) | (u32)(~(u32)j);
}
__device__ __forceinline__ u64 wredmax64(u64 k) {
#pragma unroll
    for (int off = 32; off > 0; off >>= 1) {
        u64 o = __shfl_xor(k, off);
        if (o > k) k = o;
    }
    return k;
}
__device__ __forceinline__ int binfull(float s) {
    int full = (int)(s * 262144.0f);          // 2^18 fine resolution, monotone
    return full > 262143 ? 262143 : full;
}
__device__ __forceinline__ int bin256(float s) { return binfull(s) >> 10; }

// ---------------- Kernel Z: fast zero of summed hist + counters ----------------
__global__ __launch_bounds__(256) void zero_kernel(u32* __restrict__ p, int nwords)
{
    int i = blockIdx.x * 256 + threadIdx.x;
    if (i < nwords) p[i] = 0;
}

// ---------------- Kernel A: per-slice hist (plain store) + per-image summed hist (atomic merge) ----------------
__global__ __launch_bounds__(BLKN) void hist_kernel(
    const float* __restrict__ cls, u32* __restrict__ hist_slice_g, u32* __restrict__ hist_sum_g, int n)
{
    const int b = blockIdx.x & 7;            // same-image blocks -> same XCD
    const int slice = blockIdx.x >> 3;       // 0..31
    const int tid = threadIdx.x;
    const int F4 = (n * NCLS) >> 2;
    const int s0 = (int)(((long)slice * F4) >> 5);
    const int s1 = (int)(((long)(slice + 1) * F4) >> 5);

    __shared__ u32 lh[NCLS * NBIN];          // 20KB
    for (int i = tid; i < NCLS * NBIN; i += BLKN) lh[i] = 0;
    __syncthreads();

    const float4* p4 = (const float4*)(cls + (long)b * n * NCLS);
    for (int q = s0 + tid; q < s1; q += BLKN) {
        float4 v = p4[q];
        int f = q << 2;
        float ss[4] = {v.x, v.y, v.z, v.w};
#pragma unroll
        for (int e = 0; e < 4; ++e) {
            float sc = ss[e];
            if (sc > 0.05f) {                // strict >, like reference
                u32 c = (u32)(f + e) % NCLS;
                atomicAdd(&lh[c * NBIN + bin256(sc)], 1u);
            }
        }
    }
    __syncthreads();
    u32* dst = hist_slice_g + (long)(b * NSLICE + slice) * (NCLS * NBIN);
    for (int i = tid; i < NCLS * NBIN; i += BLKN) {
        u32 v = lh[i];
        dst[i] = v;                                         // exclusive store, no pre-zero needed
        if (v) atomicAdd(&hist_sum_g[(b * NCLS + (i >> 8)) * NBIN + (i & 255)], v);
    }
}

// ---------------- Kernel B: collect — single cls pass; own counts from own slice hist ----------------
__global__ __launch_bounds__(BLKN) void collect_kernel(
    const float* __restrict__ cls, const u32* __restrict__ hist_sum_g,
    const u32* __restrict__ hist_slice_g,
    u64* __restrict__ keys_g, u32* __restrict__ cntHi, u32* __restrict__ cntLo, int n)
{
    const int b = blockIdx.x & 7;
    const int slice = blockIdx.x >> 3;
    const int tid = threadIdx.x;
    const int lane = tid & 63;
    const int wv = tid >> 6;

    __shared__ u32 sumh[NCLS * NBIN];        // 20KB (per-image summed hist)
    __shared__ int thrB[NCLS];
    __shared__ int cAs[NCLS];
    __shared__ u32 lcHi[NCLS], lcLo[NCLS], baseHi[NCLS], baseLo[NCLS];

    for (int i = tid; i < NCLS * NBIN; i += BLKN) sumh[i] = hist_sum_g[b * (NCLS * NBIN) + i];
    __syncthreads();

    // per-class threshold from summed hist (suffix scan, 4 bins/lane, wave per class)
    for (int c = wv; c < NCLS; c += 8) {
        u32 h0 = sumh[c * NBIN + 4 * lane],     h1 = sumh[c * NBIN + 4 * lane + 1],
            h2 = sumh[c * NBIN + 4 * lane + 2], h3 = sumh[c * NBIN + 4 * lane + 3];
        int acc = (int)(h0 + h1 + h2 + h3);
#pragma unroll
        for (int d = 1; d < 64; d <<= 1) { int o = __shfl_down(acc, d); if (lane + d < 64) acc += o; }
        int S0 = acc, S1 = S0 - (int)h0, S2 = S1 - (int)h1, S3 = S2 - (int)h2, S4 = S3 - (int)h3;
        if (lane == 0) { thrB[c] = -1; cAs[c] = 0; }
        int bin = -1, ca = 0;
        if      (S0 >= KTARGET && S1 < KTARGET) { bin = 4 * lane;     ca = S1; }
        else if (S1 >= KTARGET && S2 < KTARGET) { bin = 4 * lane + 1; ca = S2; }
        else if (S2 >= KTARGET && S3 < KTARGET) { bin = 4 * lane + 2; ca = S3; }
        else if (S3 >= KTARGET && S4 < KTARGET) { bin = 4 * lane + 3; ca = S4; }
        if (bin >= 0) { thrB[c] = bin; cAs[c] = ca; }
    }
    __syncthreads();

    // own-slice hi/lo counts from this block's slice histogram (20 x 1KB coalesced rows, L2-hit)
    const u32* myh = hist_slice_g + (long)(b * NSLICE + slice) * (NCLS * NBIN);
    for (int c = wv; c < NCLS; c += 8) {
        const int B = thrB[c];
        u32 h0 = myh[c * NBIN + 4 * lane],     h1 = myh[c * NBIN + 4 * lane + 1],
            h2 = myh[c * NBIN + 4 * lane + 2], h3 = myh[c * NBIN + 4 * lane + 3];
        const int bin0 = 4 * lane;
        u32 part = 0;
        if (bin0     > B) part += h0;
        if (bin0 + 1 > B) part += h1;
        if (bin0 + 2 > B) part += h2;
        if (bin0 + 3 > B) part += h3;
        u32 lov = 0;
        if (B >= 0 && (B >> 2) == lane) lov = (B & 3) == 0 ? h0 : (B & 3) == 1 ? h1 : (B & 3) == 2 ? h2 : h3;
#pragma unroll
        for (int off = 32; off > 0; off >>= 1) {
            part += __shfl_xor(part, off);
            lov  += __shfl_xor(lov,  off);
        }
        if (lane == 0) { lcHi[c] = part; lcLo[c] = lov; }
    }
    __syncthreads();

    // bulk reservation: ONE global atomic per (class, block) on padded counters
    if (tid < NCLS) {
        const int pair = b * NCLS + tid;
        u32 h = lcHi[tid], l = lcLo[tid];
        baseHi[tid] = h ? atomicAdd(&cntHi[pair * CSTR], h) : 0u;
        baseLo[tid] = l ? atomicAdd(&cntLo[pair * CSTR], l) : 0u;
        lcHi[tid] = 0; lcLo[tid] = 0;
    }
    __syncthreads();

    // single write pass over this cls slice (LDS-local ranks into reserved ranges)
    const int F4 = (n * NCLS) >> 2;
    const int s0 = (int)(((long)slice * F4) >> 5);
    const int s1 = (int)(((long)(slice + 1) * F4) >> 5);
    const float4* p4 = (const float4*)(cls + (long)b * n * NCLS);
    for (int q = s0 + tid; q < s1; q += BLKN) {
        float4 v = p4[q];
        int f = q << 2;
        float ss[4] = {v.x, v.y, v.z, v.w};
#pragma unroll
        for (int e = 0; e < 4; ++e) {
            float sc = ss[e];
            if (sc > 0.05f) {
                u32 fe = (u32)(f + e);
                u32 c = fe % NCLS;
                int row = (int)(fe / NCLS);
                int bn = bin256(sc), B = thrB[c];
                const int pair = b * NCLS + (int)c;
                if (bn > B) {
                    u32 r = atomicAdd(&lcHi[c], 1u);
                    keys_g[(long)pair * KMAX + baseHi[c] + r] = packkey(sc, row);
                } else if (bn == B) {
                    u32 r = atomicAdd(&lcLo[c], 1u);
                    int pos = KMAX - 1 - (int)(baseLo[c] + r);
                    if (pos >= cAs[c]) keys_g[(long)pair * KMAX + pos] = packkey(sc, row);
                }
            }
        }
    }
}

// ---------------- hybrid bitonic helpers ----------------
__device__ __forceinline__ u64 cmb(u64 e, u64 p, int i, int jj, int k2) {
    bool up = ((i & k2) == 0);
    bool low = ((i & jj) == 0);
    return (up == low) ? (e > p ? e : p) : (e < p ? e : p);
}
// 512 u64, 1/thread (tid<512 active), any block >=512: jj<=32 shfl, jj in {64,128,256} ping-pong LDS.
__device__ __forceinline__ void sort512_1(u64& e, int tid, u64* bufA, u64* bufB) {
    int parity = 0;
    for (int k2 = 2; k2 <= KMAX; k2 <<= 1) {
        for (int jj = k2 >> 1; jj > 0; jj >>= 1) {
            if (jj >= 64) {
                u64* buf = parity ? bufB : bufA; parity ^= 1;
                if (tid < KMAX) buf[tid] = e;
                __syncthreads();
                if (tid < KMAX) { u64 p = buf[tid ^ jj]; e = cmb(e, p, tid, jj, k2); }
            } else {
                if (tid < KMAX) { u64 p = __shfl_xor(e, jj); e = cmb(e, p, tid, jj, k2); }
            }
        }
    }
    __syncthreads();
    if (tid < KMAX) bufA[tid] = e;           // final sorted array -> bufA
    __syncthreads();
}

// ---------------- Kernel C: per-pair sort + greedy (reference-exact) ----------------
template<bool PRE>
__global__ __launch_bounds__(BLKC, 1) void nms_final_kernel(
    const float4* __restrict__ boxes,
    const float*  __restrict__ cls,
    const u32* __restrict__ hist_sum_g,
    const u64* __restrict__ keys_g,
    const u32* __restrict__ cntHi_g, const u32* __restrict__ cntLo_g,
    float* __restrict__ sel_ws, int* __restrict__ idx_ws, int n)
{
    const int b = blockIdx.x & 7;
    const int c = blockIdx.x >> 3;
    const int pair = b * NCLS + c;
    const int tid = threadIdx.x;
    const int lane = tid & 63;
    const int wv = tid >> 6;                 // 0..15

    const float4* bb = boxes + (long)b * n;
    const float* srow = cls + (long)b * n * NCLS + c;   // strided (fallback rounds only)
    float* selp = sel_ws + pair * MAXDET;
    int*   idxp = idx_ws + pair * MAXDET;

    __shared__ u64    keysA[KMAX], keysB[KMAX];   // 8KB
    __shared__ float4 cbox[KMAX];                 // 8KB: candidate boxes (preloaded)
    __shared__ float4 aBox[MAXDET];               // 4.8KB: accepted boxes
    __shared__ u32    hist256[NBIN];
    __shared__ u32    kb0[64], kb1[64], psupm[2];
    __shared__ u64    wl[16];
    __shared__ int    ctrl[8];   // 0:B 1:cumAbove 2:cumTotal 3:cntLo 4:cntHi 5:k
    __shared__ u64    ubk;

    if (tid == 0) { ubk = ~0ull; ctrl[5] = 0; }
    if (tid < 64) { kb0[tid] = 0; kb1[tid] = 0; }
    if (tid < 2)  psupm[tid] = 0;
    bool first = true;
    __syncthreads();

    while (true) {
        const u64 UB = ubk;
        u64 e = 0;
        int trusted, cumTotal, cumAbove;

        if (PRE && first) {
            if (tid < NBIN) hist256[tid] = hist_sum_g[pair * NBIN + tid];
            __syncthreads();
            if (wv == 0) {
                u32 h0 = hist256[4 * lane], h1 = hist256[4 * lane + 1],
                    h2 = hist256[4 * lane + 2], h3 = hist256[4 * lane + 3];
                int acc = (int)(h0 + h1 + h2 + h3);
#pragma unroll
                for (int d = 1; d < 64; d <<= 1) { int o = __shfl_down(acc, d); if (lane + d < 64) acc += o; }
                int S0 = acc, S1 = S0 - (int)h0, S2 = S1 - (int)h1, S3 = S2 - (int)h2, S4 = S3 - (int)h3;
                if (lane == 0) { ctrl[0] = -1; ctrl[1] = 0; ctrl[2] = S0; }
                int bin = -1, ca = 0;
                if      (S0 >= KTARGET && S1 < KTARGET) { bin = 4 * lane;     ca = S1; }
                else if (S1 >= KTARGET && S2 < KTARGET) { bin = 4 * lane + 1; ca = S2; }
                else if (S2 >= KTARGET && S3 < KTARGET) { bin = 4 * lane + 2; ca = S3; }
                else if (S3 >= KTARGET && S4 < KTARGET) { bin = 4 * lane + 3; ca = S4; }
                if (bin >= 0) { ctrl[0] = bin; ctrl[1] = ca; }
            }
            __syncthreads();
            cumTotal = ctrl[2];
            if (cumTotal == 0) break;
            cumAbove = ctrl[1];
            const int hi = (int)cntHi_g[pair * CSTR];
            const int lo = (int)cntLo_g[pair * CSTR];
            const bool dropped = lo > (KMAX - cumAbove);
            trusted = dropped ? cumAbove : (hi + lo);
            const int lo_start = dropped ? cumAbove : (KMAX - lo);
            if (tid < KMAX && (tid < hi || tid >= lo_start)) e = keys_g[(long)pair * KMAX + tid];
            if (trusted > 0) {
                sort512_1(e, tid, keysA, keysB);
            } else {
                // boundary overflow w/ empty hi region: single best key < UB (progress)
                u64 lb = 0;
                for (int j = tid; j < n; j += BLKC) {
                    float sc = srow[(long)j * NCLS];
                    if (sc > 0.05f) { u64 ky = packkey(sc, j); if (ky < UB && ky > lb) lb = ky; }
                }
                lb = wredmax64(lb);
                if (lane == 0) wl[wv] = lb;
                __syncthreads();
                if (tid == 0) { u64 bk = 0; for (int w = 0; w < 16; ++w) if (wl[w] > bk) bk = wl[w]; keysA[0] = bk; }
                trusted = 1;
                __syncthreads();
            }
        } else {
            // ---- fallback rounds: full strided rescan (rare; correctness path) ----
            if (tid < NBIN) hist256[tid] = 0;
            if (tid < KMAX) keysA[tid] = 0;
            if (tid > 0 && tid < 5) ctrl[tid] = 0;
            if (tid == 0) ctrl[0] = -1;
            __syncthreads();
            for (int j = tid; j < n; j += BLKC) {
                float sc = srow[(long)j * NCLS];
                if (sc > 0.05f) { u64 ky = packkey(sc, j); if (ky < UB) atomicAdd(&hist256[bin256(sc)], 1u); }
            }
            __syncthreads();
            if (wv == 0) {
                u32 h0 = hist256[4 * lane], h1 = hist256[4 * lane + 1],
                    h2 = hist256[4 * lane + 2], h3 = hist256[4 * lane + 3];
                int acc = (int)(h0 + h1 + h2 + h3);
#pragma unroll
                for (int d = 1; d < 64; d <<= 1) { int o = __shfl_down(acc, d); if (lane + d < 64) acc += o; }
                int S0 = acc, S1 = S0 - (int)h0, S2 = S1 - (int)h1, S3 = S2 - (int)h2, S4 = S3 - (int)h3;
                if (lane == 0) { ctrl[0] = -1; ctrl[1] = 0; ctrl[2] = S0; }
                int bin = -1, ca = 0;
                if      (S0 >= KTARGET && S1 < KTARGET) { bin = 4 * lane;     ca = S1; }
                else if (S1 >= KTARGET && S2 < KTARGET) { bin = 4 * lane + 1; ca = S2; }
                else if (S2 >= KTARGET && S3 < KTARGET) { bin = 4 * lane + 2; ca = S3; }
                else if (S3 >= KTARGET && S4 < KTARGET) { bin = 4 * lane + 3; ca = S4; }
                if (bin >= 0) { ctrl[0] = bin; ctrl[1] = ca; }
            }
            __syncthreads();
            cumTotal = ctrl[2];
            if (cumTotal == 0) break;
            cumAbove = ctrl[1];
            const int B = ctrl[0];
            for (int j = tid; j < n; j += BLKC) {
                float sc = srow[(long)j * NCLS];
                if (sc > 0.05f) {
                    u64 ky = packkey(sc, j);
                    if (ky < UB) {
                        int bn = bin256(sc);
                        if (bn > B) { int sl = atomicAdd(&ctrl[4], 1); if (sl < KMAX) keysA[sl] = ky; }
                        else if (bn == B) {
                            int p = atomicAdd(&ctrl[3], 1);
                            int pos = KMAX - 1 - p;
                            if (pos >= cumAbove) keysA[pos] = ky;
                        }
                    }
                }
            }
            __syncthreads();
            const int cLo = ctrl[3], cHi = ctrl[4];
            const bool dropped = (cHi + cLo) > KMAX;
            trusted = dropped ? cHi : (cHi + cLo);
            if (trusted > 0) {
                if (tid < KMAX) e = keysA[tid];
                __syncthreads();
                sort512_1(e, tid, keysA, keysB);
            } else {
                u64 lb = 0;
                for (int j = tid; j < n; j += BLKC) {
                    float sc = srow[(long)j * NCLS];
                    if (sc > 0.05f) { u64 ky = packkey(sc, j); if (ky < UB && ky > lb) lb = ky; }
                }
                lb = wredmax64(lb);
                if (lane == 0) wl[wv] = lb;
                __syncthreads();
                if (tid == 0) { u64 bk = 0; for (int w = 0; w < 16; ++w) if (wl[w] > bk) bk = wl[w]; keysA[0] = bk; }
                trusted = 1;
                __syncthreads();
            }
        }

        // ---- preload ALL candidate boxes (one wide gather, off the per-chunk critical path) ----
        if (tid < KMAX) {
            u64 ky = (tid < trusted) ? keysA[tid] : 0;
            float4 bx = make_float4(0.f, 0.f, 0.f, 0.f);
            if (tid < trusted) bx = bb[(int)(~(u32)ky)];
            cbox[tid] = bx;
        }
        __syncthreads();

        // ---- greedy over sorted prefix: 2 barriers/chunk ----
        for (int base = 0; base < trusted; base += 64) {
            const int kcur = ctrl[5];        // uniform (after barrier)
            if (kcur >= MAXDET) break;
            const int ci = base + lane;
            const bool have = ci < trusted;
            const float4 pb = cbox[have ? ci : 0];
            const float par = (pb.z - pb.x) * (pb.w - pb.y);

            // (a) candidate vs prior accepted, split across 16 waves; float4 broadcast + exact f64 cmp
            bool sup = false;
            for (int a = wv; a < kcur; a += 16) {
                float4 ab = aBox[a];
                float am = (ab.z - ab.x) * (ab.w - ab.y);
                float ltx = fmaxf(ab.x, pb.x), lty = fmaxf(ab.y, pb.y);
                float rbx = fminf(ab.z, pb.z), rby = fminf(ab.w, pb.w);
                float wx = fmaxf(rbx - ltx, 0.0f), wy = fmaxf(rby - lty, 0.0f);
                float inter = wx * wy;
                float den = ((par + am) - inter) + 1e-9f;   // ref op order
                sup = sup || ((double)inter > T_MID * (double)den);
            }
            u64 bal = __ballot(sup && have);
            if (lane == 0 && bal) { atomicOr(&psupm[0], (u32)bal); atomicOr(&psupm[1], (u32)(bal >> 32)); }

            // (b) in-chunk kill matrix: killer=lane, victim m; 16 waves x 4 victims
#pragma unroll
            for (int r = 0; r < 4; ++r) {
                const int m = (r << 4) | wv;
                if (lane < m && (base + m) < trusted) {     // lane<m => lane has a real candidate
                    float4 vb = cbox[base + m];
                    float va = (vb.z - vb.x) * (vb.w - vb.y);
                    float ltx = fmaxf(pb.x, vb.x), lty = fmaxf(pb.y, vb.y);
                    float rbx = fminf(pb.z, vb.z), rby = fminf(pb.w, vb.w);
                    float wx = fmaxf(rbx - ltx, 0.0f), wy = fmaxf(rby - lty, 0.0f);
                    float inter = wx * wy;
                    float den = ((va + par) - inter) + 1e-9f;  // victim area first (ref order)
                    if ((double)inter > T_MID * (double)den) {
                        if (lane < 32) atomicOr(&kb0[m], 1u << lane);
                        else           atomicOr(&kb1[m], 1u << (lane - 32));
                    }
                }
            }
            __syncthreads();                 // bar 1

            // (c) wave 0: ballot fixpoint (== sequential greedy), accept, clear masks
            if (tid < 64) {
                const u64 kbm = ((u64)kb1[lane] << 32) | kb0[lane];
                const u64 ps  = ((u64)psupm[1] << 32) | psupm[0];
                const bool alive0 = have && !((ps >> lane) & 1);
                u64 accm = __ballot(alive0);
                for (int it = 0; it < 64; ++it) {
                    u64 nm = __ballot(alive0 && ((kbm & accm) == 0ull));
                    if (nm == accm) break;
                    accm = nm;
                }
                const bool a = (accm >> lane) & 1;
                const int rank = (int)__popcll(accm & ((1ull << lane) - 1ull));
                const int rem = MAXDET - kcur;
                if (a && rank < rem) {
                    const int slot = kcur + rank;
                    aBox[slot] = pb;
                    const u64 ky = keysA[ci];
                    selp[slot] = __uint_as_float((u32)(ky >> 32) ^ 0x80000000u);
                    idxp[slot] = (int)(~(u32)ky);
                }
                kb0[lane] = 0; kb1[lane] = 0;
                if (lane < 2) psupm[lane] = 0;
                if (lane == 0) {
                    const int cnt = (int)__popcll(accm);
                    ctrl[5] = kcur + (cnt < rem ? cnt : rem);
                }
            }
            __syncthreads();                 // bar 2
        }

        if (tid == 0) ubk = keysA[trusted - 1];
        first = false;
        __syncthreads();
        if (ctrl[5] >= MAXDET || cumTotal - trusted <= 0) break;
    }

    const int kfin = ctrl[5];
    for (int f = kfin + tid; f < MAXDET; f += BLKC) { selp[f] = NEGV; idxp[f] = 0; }
}

// ---------------- Kernel D: per-image global top-300 via 2-level select + gather (1024 thr) ----------------
#define OFF_B3D (NB * MAXDET * 4)
#define OFF_SC  (OFF_B3D + NB * MAXDET * 16)
#define OFF_LAB (OFF_SC + NB * MAXDET)

__global__ __launch_bounds__(1024, 1) void topk_kernel(
    const float4* __restrict__ boxes,
    const float*  __restrict__ b3d,
    const float*  __restrict__ sel_ws,
    const int*    __restrict__ idx_ws,
    float* __restrict__ out,
    int n)
{
    const int b = blockIdx.x;
    const int tid = threadIdx.x;
    const int lane = tid & 63;
    const int wv = tid >> 6;                  // 0..15
    const int M = NCLS * MAXDET;              // 6000

    __shared__ u64  kall[NCLS * MAXDET];      // 48KB
    __shared__ u32  h1[512];
    __shared__ u64  keysA[512], keysB[512];
    __shared__ int  wts[8], ews[8];
    __shared__ int  ctrl[8];
    __shared__ int  outA[MAXDET];

    const float* sp = sel_ws + b * M;
    for (int f = tid; f < M; f += 1024) {
        float v = sp[f];
        kall[f] = (v > 0.05f) ? packkey(v, f) : 0ull;
    }
    if (tid < 512) { h1[tid] = 0; keysA[tid] = 0; }
    if (tid > 0 && tid < 8) ctrl[tid] = 0;
    if (tid == 0) { ctrl[0] = -1; ctrl[5] = -1; }
    __syncthreads();

    for (int f = tid; f < M; f += 1024) {
        u64 k = kall[f];
        if (k) {
            float s = __uint_as_float((u32)(k >> 32) ^ 0x80000000u);
            atomicAdd(&h1[binfull(s) >> 9], 1u);
        }
    }
    __syncthreads();
    {
        const int h = (tid < 512) ? (int)h1[tid] : 0;
        int acc = h;
#pragma unroll
        for (int d = 1; d < 64; d <<= 1) { int o = __shfl_down(acc, d); if (lane + d < 64) acc += o; }
        if (lane == 0 && wv < 8) wts[wv] = acc;
        __syncthreads();
        if (tid < 8) { int e = 0; for (int w = tid + 1; w < 8; ++w) e += wts[w]; ews[tid] = e; }
        __syncthreads();
        if (tid < 512) {
            const int S = acc + ews[wv];
            if (S >= MAXDET && (S - h) < MAXDET) { ctrl[0] = tid; ctrl[1] = S - h; }
            if (tid == 0) ctrl[2] = S;
        }
    }
    __syncthreads();
    const int B1 = ctrl[0];
    const int cA1 = ctrl[1];

    if (tid < 512) h1[tid] = 0;
    __syncthreads();
    if (B1 >= 0) {
        for (int f = tid; f < M; f += 1024) {
            u64 k = kall[f];
            if (k) {
                float s = __uint_as_float((u32)(k >> 32) ^ 0x80000000u);
                int full = binfull(s);
                if ((full >> 9) == B1) atomicAdd(&h1[full & 511], 1u);
            }
        }
    }
    __syncthreads();
    const int KT2 = MAXDET - cA1;
    {
        const int h = (tid < 512) ? (int)h1[tid] : 0;
        int acc = h;
#pragma unroll
        for (int d = 1; d < 64; d <<= 1) { int o = __shfl_down(acc, d); if (lane + d < 64) acc += o; }
        if (lane == 0 && wv < 8) wts[wv] = acc;
        __syncthreads();
        if (tid < 8) { int e = 0; for (int w = tid + 1; w < 8; ++w) e += wts[w]; ews[tid] = e; }
        __syncthreads();
        if (tid < 512) {
            const int S = acc + ews[wv];
            if (B1 >= 0 && S >= KT2 && (S - h) < KT2) { ctrl[5] = tid; ctrl[6] = S - h; }
        }
    }
    __syncthreads();
    const int B2 = ctrl[5];
    const int cA2 = ctrl[6];

    for (int f = tid; f < M; f += 1024) {
        u64 k = kall[f];
        if (k) {
            float s = __uint_as_float((u32)(k >> 32) ^ 0x80000000u);
            int full = binfull(s);
            int bkt = full >> 9, sub = full & 511;
            bool hi = (B1 < 0) || (bkt > B1) || (bkt == B1 && sub > B2);
            bool lo = (B1 >= 0) && (bkt == B1) && (sub == B2);
            if (hi) { int slot = atomicAdd(&ctrl[3], 1); if (slot < 512) keysA[slot] = k; }
            else if (lo) { int p = atomicAdd(&ctrl[4], 1); int pos = 511 - p; if (pos >= cA1 + cA2) keysA[pos] = k; }
        }
    }
    __syncthreads();
    const bool dropped = (ctrl[3] + ctrl[4]) > 512;

    if (!dropped) {
        u64 e = (tid < 512) ? keysA[tid] : 0;
        int parity = 0;
        for (int k2 = 2; k2 <= 512; k2 <<= 1) {
            for (int jj = k2 >> 1; jj > 0; jj >>= 1) {
                if (jj >= 64) {
                    u64* buf = parity ? keysB : keysA; parity ^= 1;
                    if (tid < 512) buf[tid] = e;
                    __syncthreads();
                    if (tid < 512) { u64 p = buf[tid ^ jj]; e = cmb(e, p, tid, jj, k2); }
                } else {
                    if (tid < 512) { u64 p = __shfl_xor(e, jj); e = cmb(e, p, tid, jj, k2); }
                }
            }
        }
        __syncthreads();
        if (tid < 512) keysA[tid] = e;
        __syncthreads();
    } else {
        if (tid < 64) {
            int pos = 0;
            for (int k = 0; k < MAXDET; ++k) {
                u64 key = 0;
                if (lane < NCLS && pos < MAXDET) key = kall[lane * MAXDET + pos];
                u64 r = wredmax64(key);
                if (r != 0) {
                    u64 bal = __ballot(key == r);
                    int w = __ffsll((long long)bal) - 1;
                    if (lane == w) pos++;
                }
                if (lane == 0) keysA[k] = r;
            }
        }
        __syncthreads();
    }

    for (int k = tid; k < MAXDET; k += 1024) {
        const u64 kk = keysA[k];
        const bool ok = kk != 0;
        const int flat = (int)(~(u32)kk);
        const float sc = __uint_as_float((u32)(kk >> 32) ^ 0x80000000u);
        const int a = ok ? idx_ws[b * M + flat] : -1;
        const int cc = flat / MAXDET;
        float4 bx = make_float4(-1.f, -1.f, -1.f, -1.f);
        if (ok) bx = boxes[(long)b * n + a];
        out[(long)b * MAXDET * 4 + k * 4 + 0] = bx.x;
        out[(long)b * MAXDET * 4 + k * 4 + 1] = bx.y;
        out[(long)b * MAXDET * 4 + k * 4 + 2] = bx.z;
        out[(long)b * MAXDET * 4 + k * 4 + 3] = bx.w;
        out[OFF_SC  + (long)b * MAXDET + k] = ok ? sc : -1.0f;
        out[OFF_LAB + (long)b * MAXDET + k] = ok ? (float)cc : -1.0f;
        outA[k] = a;
    }
    __syncthreads();
    for (int q = tid; q < MAXDET * 16; q += 1024) {
        const int k = q >> 4;
        const int a = outA[k];
        out[OFF_B3D + (long)b * MAXDET * 16 + q] = (a >= 0) ? b3d[((long)b * n + a) * 16 + (q & 15)] : -1.0f;
    }
}

extern "C" void kernel_launch(void* const* d_in, const int* in_sizes, int n_in,
                              void* d_out, int out_size, void* d_ws, size_t ws_size,
                              hipStream_t stream)
{
    const float* boxes = (const float*)d_in[0];   // [8, N, 4]
    const float* b3d   = (const float*)d_in[1];   // [8, N, 16]
    const float* cls   = (const float*)d_in[2];   // [8, N, 20]
    float* out = (float*)d_out;

    const int n = in_sizes[0] / (NB * 4);         // 49104
    const int NP = NB * NCLS;                     // 160

    const size_t sumB   = (size_t)NP * NBIN * sizeof(u32);                   // 160KB
    const size_t cntB   = (size_t)NP * CSTR * sizeof(u32);                   // 10KB each
    const size_t sliceB = (size_t)NB * NSLICE * NCLS * NBIN * sizeof(u32);   // 5.24MB
    const size_t keysB_ = (size_t)NP * KMAX * sizeof(u64);                   // 640KB
    const size_t selB   = (size_t)NP * MAXDET * sizeof(float);

    char* p = (char*)d_ws;
    u32*  hist_sum_g   = (u32*)p;          p += sumB;     // | contiguous zero region:
    u32*  cntHi        = (u32*)p;          p += cntB;     // | sum + cntHi + cntLo
    u32*  cntLo        = (u32*)p;          p += cntB;     // | = 46080 words
    u32*  hist_slice_g = (u32*)p;          p += sliceB;
    u64*  keys_g       = (u64*)p;          p += keysB_;
    float* sel_ws      = (float*)p;        p += selB;
    int*   idx_ws      = (int*)p;          p += selB;

    if (ws_size >= (size_t)(p - (char*)d_ws)) {
        const int zwords = (int)((sumB + 2 * cntB) / sizeof(u32));
        hipLaunchKernelGGL(zero_kernel, dim3((zwords + 255) / 256), dim3(256), 0, stream,
                           hist_sum_g, zwords);
        hipLaunchKernelGGL(hist_kernel, dim3(NB * NSLICE), dim3(BLKN), 0, stream,
                           cls, hist_slice_g, hist_sum_g, n);
        hipLaunchKernelGGL(collect_kernel, dim3(NB * NSLICE), dim3(BLKN), 0, stream,
                           cls, hist_sum_g, hist_slice_g, keys_g, cntHi, cntLo, n);
        hipLaunchKernelGGL((nms_final_kernel<true>), dim3(NP), dim3(BLKC), 0, stream,
                           (const float4*)boxes, cls, hist_sum_g, keys_g, cntHi, cntLo,
                           sel_ws, idx_ws, n);
        hipLaunchKernelGGL(topk_kernel, dim3(NB), dim3(1024), 0, stream,
                           (const float4*)boxes, b3d, sel_ws, idx_ws, out, n);
    } else {
        float* sel2 = (float*)d_ws;
        int*   idx2 = (int*)((char*)d_ws + selB);
        hipLaunchKernelGGL((nms_final_kernel<false>), dim3(NP), dim3(BLKC), 0, stream,
                           (const float4*)boxes, cls, nullptr, nullptr, nullptr, nullptr,
                           sel2, idx2, n);
        hipLaunchKernelGGL(topk_kernel, dim3(NB), dim3(1024), 0, stream,
                           (const float4*)boxes, b3d, sel2, idx2, out, n);
    }
}

// Round 14
// 93.342 us; speedup vs baseline: 1.6566x; 1.0442x over previous
//
#include <hip/hip_runtime.h>

#define NCLS    20
#define NB      8
#define MAXDET  300
#define NEGV    (-1e9f)
#define NEGH    (-5e8f)
#define BLKN    512
#define BLKC    1024
#define KTARGET 448
#define KMAX    512
#define NBIN    256
#define NSLICE  64
#define SLSH    6         // log2(NSLICE)
#define CSTR    16        // global counter stride (u32s) -> one 64B line per counter

// exact: RN_f32(inter/den) > 0.5  <=>  (double)inter > T_MID * (double)den   (den>0)
// T_MID = 0.5 + 2^-25 exactly representable; 25-bit x 24-bit product exact in f64.
#define T_MID   0x1.000001p-1

typedef unsigned long long u64;
typedef unsigned int u32;

__device__ __forceinline__ u64 packkey(float s, int j) {
    // valid scores are > 0.05 (positive): bits^0x80000000 order-preserving; ~j -> lower idx wins
    return ((u64)(__float_as_uint(s) ^ 0x80000000u) << 32) | (u32)(~(u32)j);
}
__device__ __forceinline__ u64 wredmax64(u64 k) {
#pragma unroll
    for (int off = 32; off > 0; off >>= 1) {
        u64 o = __shfl_xor(k, off);
        if (o > k) k = o;
    }
    return k;
}
__device__ __forceinline__ int binfull(float s) {
    int full = (int)(s * 262144.0f);          // 2^18 fine resolution, monotone
    return full > 262143 ? 262143 : full;
}
__device__ __forceinline__ int bin256(float s) { return binfull(s) >> 10; }

// ---------------- Kernel Z: fast zero of summed hist + counters ----------------
__global__ __launch_bounds__(256) void zero_kernel(u32* __restrict__ p, int nwords)
{
    int i = blockIdx.x * 256 + threadIdx.x;
    if (i < nwords) p[i] = 0;
}

// ---------------- Kernel A: per-slice hist (plain store) + per-image summed hist (atomic merge) ----------------
__global__ __launch_bounds__(BLKN) void hist_kernel(
    const float* __restrict__ cls, u32* __restrict__ hist_slice_g, u32* __restrict__ hist_sum_g, int n)
{
    const int b = blockIdx.x & 7;            // same-image blocks -> same XCD
    const int slice = blockIdx.x >> 3;       // 0..NSLICE-1
    const int tid = threadIdx.x;
    const int F4 = (n * NCLS) >> 2;
    const int s0 = (int)(((long)slice * F4) >> SLSH);
    const int s1 = (int)(((long)(slice + 1) * F4) >> SLSH);

    __shared__ u32 lh[NCLS * NBIN];          // 20KB
    for (int i = tid; i < NCLS * NBIN; i += BLKN) lh[i] = 0;
    __syncthreads();

    const float4* p4 = (const float4*)(cls + (long)b * n * NCLS);
    for (int q = s0 + tid; q < s1; q += BLKN) {
        float4 v = p4[q];
        int f = q << 2;
        float ss[4] = {v.x, v.y, v.z, v.w};
#pragma unroll
        for (int e = 0; e < 4; ++e) {
            float sc = ss[e];
            if (sc > 0.05f) {                // strict >, like reference
                u32 c = (u32)(f + e) % NCLS;
                atomicAdd(&lh[c * NBIN + bin256(sc)], 1u);
            }
        }
    }
    __syncthreads();
    u32* dst = hist_slice_g + (long)(b * NSLICE + slice) * (NCLS * NBIN);
    for (int i = tid; i < NCLS * NBIN; i += BLKN) {
        u32 v = lh[i];
        dst[i] = v;                                         // exclusive store, no pre-zero needed
        if (v) atomicAdd(&hist_sum_g[(b * NCLS + (i >> 8)) * NBIN + (i & 255)], v);
    }
}

// ---------------- Kernel B: collect — single cls pass; own counts from own slice hist ----------------
__global__ __launch_bounds__(BLKN) void collect_kernel(
    const float* __restrict__ cls, const u32* __restrict__ hist_sum_g,
    const u32* __restrict__ hist_slice_g,
    u64* __restrict__ keys_g, u32* __restrict__ cntHi, u32* __restrict__ cntLo,
    int4* __restrict__ meta_g, int n)
{
    const int b = blockIdx.x & 7;
    const int slice = blockIdx.x >> 3;
    const int tid = threadIdx.x;
    const int lane = tid & 63;
    const int wv = tid >> 6;

    __shared__ u32 sumh[NCLS * NBIN];        // 20KB (per-image summed hist)
    __shared__ int thrB[NCLS];
    __shared__ int cAs[NCLS];
    __shared__ int tots[NCLS];
    __shared__ u32 lcHi[NCLS], lcLo[NCLS], baseHi[NCLS], baseLo[NCLS];

    for (int i = tid; i < NCLS * NBIN; i += BLKN) sumh[i] = hist_sum_g[b * (NCLS * NBIN) + i];
    __syncthreads();

    // per-class threshold from summed hist (suffix scan, 4 bins/lane, wave per class)
    for (int c = wv; c < NCLS; c += 8) {
        u32 h0 = sumh[c * NBIN + 4 * lane],     h1 = sumh[c * NBIN + 4 * lane + 1],
            h2 = sumh[c * NBIN + 4 * lane + 2], h3 = sumh[c * NBIN + 4 * lane + 3];
        int acc = (int)(h0 + h1 + h2 + h3);
#pragma unroll
        for (int d = 1; d < 64; d <<= 1) { int o = __shfl_down(acc, d); if (lane + d < 64) acc += o; }
        int S0 = acc, S1 = S0 - (int)h0, S2 = S1 - (int)h1, S3 = S2 - (int)h2, S4 = S3 - (int)h3;
        if (lane == 0) { thrB[c] = -1; cAs[c] = 0; tots[c] = S0; }
        int bin = -1, ca = 0;
        if      (S0 >= KTARGET && S1 < KTARGET) { bin = 4 * lane;     ca = S1; }
        else if (S1 >= KTARGET && S2 < KTARGET) { bin = 4 * lane + 1; ca = S2; }
        else if (S2 >= KTARGET && S3 < KTARGET) { bin = 4 * lane + 2; ca = S3; }
        else if (S3 >= KTARGET && S4 < KTARGET) { bin = 4 * lane + 3; ca = S4; }
        if (bin >= 0) { thrB[c] = bin; cAs[c] = ca; }
    }
    __syncthreads();

    // slice 0 publishes per-pair meta for kernel C (identical values computed on every block)
    if (slice == 0 && tid < NCLS) {
        meta_g[b * NCLS + tid] = make_int4(thrB[tid], cAs[tid], tots[tid], 0);
    }

    // own-slice hi/lo counts from this block's slice histogram (20 x 1KB coalesced rows, L2-hit)
    const u32* myh = hist_slice_g + (long)(b * NSLICE + slice) * (NCLS * NBIN);
    for (int c = wv; c < NCLS; c += 8) {
        const int B = thrB[c];
        u32 h0 = myh[c * NBIN + 4 * lane],     h1 = myh[c * NBIN + 4 * lane + 1],
            h2 = myh[c * NBIN + 4 * lane + 2], h3 = myh[c * NBIN + 4 * lane + 3];
        const int bin0 = 4 * lane;
        u32 part = 0;
        if (bin0     > B) part += h0;
        if (bin0 + 1 > B) part += h1;
        if (bin0 + 2 > B) part += h2;
        if (bin0 + 3 > B) part += h3;
        u32 lov = 0;
        if (B >= 0 && (B >> 2) == lane) lov = (B & 3) == 0 ? h0 : (B & 3) == 1 ? h1 : (B & 3) == 2 ? h2 : h3;
#pragma unroll
        for (int off = 32; off > 0; off >>= 1) {
            part += __shfl_xor(part, off);
            lov  += __shfl_xor(lov,  off);
        }
        if (lane == 0) { lcHi[c] = part; lcLo[c] = lov; }
    }
    __syncthreads();

    // bulk reservation: ONE global atomic per (class, block) on padded counters
    if (tid < NCLS) {
        const int pair = b * NCLS + tid;
        u32 h = lcHi[tid], l = lcLo[tid];
        baseHi[tid] = h ? atomicAdd(&cntHi[pair * CSTR], h) : 0u;
        baseLo[tid] = l ? atomicAdd(&cntLo[pair * CSTR], l) : 0u;
        lcHi[tid] = 0; lcLo[tid] = 0;
    }
    __syncthreads();

    // single write pass over this cls slice (LDS-local ranks into reserved ranges)
    const int F4 = (n * NCLS) >> 2;
    const int s0 = (int)(((long)slice * F4) >> SLSH);
    const int s1 = (int)(((long)(slice + 1) * F4) >> SLSH);
    const float4* p4 = (const float4*)(cls + (long)b * n * NCLS);
    for (int q = s0 + tid; q < s1; q += BLKN) {
        float4 v = p4[q];
        int f = q << 2;
        float ss[4] = {v.x, v.y, v.z, v.w};
#pragma unroll
        for (int e = 0; e < 4; ++e) {
            float sc = ss[e];
            if (sc > 0.05f) {
                u32 fe = (u32)(f + e);
                u32 c = fe % NCLS;
                int row = (int)(fe / NCLS);
                int bn = bin256(sc), B = thrB[c];
                const int pair = b * NCLS + (int)c;
                if (bn > B) {
                    u32 r = atomicAdd(&lcHi[c], 1u);
                    keys_g[(long)pair * KMAX + baseHi[c] + r] = packkey(sc, row);
                } else if (bn == B) {
                    u32 r = atomicAdd(&lcLo[c], 1u);
                    int pos = KMAX - 1 - (int)(baseLo[c] + r);
                    if (pos >= cAs[c]) keys_g[(long)pair * KMAX + pos] = packkey(sc, row);
                }
            }
        }
    }
}

// ---------------- hybrid bitonic helpers ----------------
__device__ __forceinline__ u64 cmb(u64 e, u64 p, int i, int jj, int k2) {
    bool up = ((i & k2) == 0);
    bool low = ((i & jj) == 0);
    return (up == low) ? (e > p ? e : p) : (e < p ? e : p);
}
// 512 u64, 1/thread (tid<512 active), any block >=512: jj<=32 shfl, jj in {64,128,256} ping-pong LDS.
__device__ __forceinline__ void sort512_1(u64& e, int tid, u64* bufA, u64* bufB) {
    int parity = 0;
    for (int k2 = 2; k2 <= KMAX; k2 <<= 1) {
        for (int jj = k2 >> 1; jj > 0; jj >>= 1) {
            if (jj >= 64) {
                u64* buf = parity ? bufB : bufA; parity ^= 1;
                if (tid < KMAX) buf[tid] = e;
                __syncthreads();
                if (tid < KMAX) { u64 p = buf[tid ^ jj]; e = cmb(e, p, tid, jj, k2); }
            } else {
                if (tid < KMAX) { u64 p = __shfl_xor(e, jj); e = cmb(e, p, tid, jj, k2); }
            }
        }
    }
    __syncthreads();
    if (tid < KMAX) bufA[tid] = e;           // final sorted array -> bufA
    __syncthreads();
}

// ---------------- Kernel C: per-pair sort + greedy (reference-exact) ----------------
template<bool PRE>
__global__ __launch_bounds__(BLKC, 1) void nms_final_kernel(
    const float4* __restrict__ boxes,
    const float*  __restrict__ cls,
    const u64* __restrict__ keys_g,
    const int4* __restrict__ meta_g,
    const u32* __restrict__ cntHi_g, const u32* __restrict__ cntLo_g,
    float* __restrict__ sel_ws, int* __restrict__ idx_ws, int n)
{
    const int b = blockIdx.x & 7;
    const int c = blockIdx.x >> 3;
    const int pair = b * NCLS + c;
    const int tid = threadIdx.x;
    const int lane = tid & 63;
    const int wv = tid >> 6;                 // 0..15

    const float4* bb = boxes + (long)b * n;
    const float* srow = cls + (long)b * n * NCLS + c;   // strided (fallback rounds only)
    float* selp = sel_ws + pair * MAXDET;
    int*   idxp = idx_ws + pair * MAXDET;

    __shared__ u64    keysA[KMAX], keysB[KMAX];   // 8KB
    __shared__ float4 cbox[KMAX];                 // 8KB: candidate boxes (preloaded)
    __shared__ float4 aBox[MAXDET];               // 4.8KB: accepted boxes
    __shared__ u32    hist256[NBIN];
    __shared__ u32    kb0[64], kb1[64], psupm[2];
    __shared__ u64    wl[16];
    __shared__ int    ctrl[8];   // 0:B 1:cumAbove 2:cumTotal 3:cntLo 4:cntHi 5:k
    __shared__ u64    ubk;

    if (tid == 0) { ubk = ~0ull; ctrl[5] = 0; }
    if (tid < 64) { kb0[tid] = 0; kb1[tid] = 0; }
    if (tid < 2)  psupm[tid] = 0;
    bool first = true;
    __syncthreads();

    while (true) {
        const u64 UB = ubk;
        u64 e = 0;
        int trusted, cumTotal, cumAbove;

        if (PRE && first) {
            const int4 m = meta_g[pair];     // {B, cumAbove, total, -}
            cumTotal = m.z;
            if (cumTotal == 0) break;
            cumAbove = m.y;
            const int hi = (int)cntHi_g[pair * CSTR];
            const int lo = (int)cntLo_g[pair * CSTR];
            const bool dropped = lo > (KMAX - cumAbove);
            trusted = dropped ? cumAbove : (hi + lo);
            const int lo_start = dropped ? cumAbove : (KMAX - lo);
            if (tid < KMAX && (tid < hi || tid >= lo_start)) e = keys_g[(long)pair * KMAX + tid];
            if (trusted > 0) {
                sort512_1(e, tid, keysA, keysB);
            } else {
                // boundary overflow w/ empty hi region: single best key < UB (progress)
                u64 lb = 0;
                for (int j = tid; j < n; j += BLKC) {
                    float sc = srow[(long)j * NCLS];
                    if (sc > 0.05f) { u64 ky = packkey(sc, j); if (ky < UB && ky > lb) lb = ky; }
                }
                lb = wredmax64(lb);
                if (lane == 0) wl[wv] = lb;
                __syncthreads();
                if (tid == 0) { u64 bk = 0; for (int w = 0; w < 16; ++w) if (wl[w] > bk) bk = wl[w]; keysA[0] = bk; }
                trusted = 1;
                __syncthreads();
            }
        } else {
            // ---- fallback rounds: full strided rescan (rare; correctness path) ----
            if (tid < NBIN) hist256[tid] = 0;
            if (tid < KMAX) keysA[tid] = 0;
            if (tid > 0 && tid < 5) ctrl[tid] = 0;
            if (tid == 0) ctrl[0] = -1;
            __syncthreads();
            for (int j = tid; j < n; j += BLKC) {
                float sc = srow[(long)j * NCLS];
                if (sc > 0.05f) { u64 ky = packkey(sc, j); if (ky < UB) atomicAdd(&hist256[bin256(sc)], 1u); }
            }
            __syncthreads();
            if (wv == 0) {
                u32 h0 = hist256[4 * lane], h1 = hist256[4 * lane + 1],
                    h2 = hist256[4 * lane + 2], h3 = hist256[4 * lane + 3];
                int acc = (int)(h0 + h1 + h2 + h3);
#pragma unroll
                for (int d = 1; d < 64; d <<= 1) { int o = __shfl_down(acc, d); if (lane + d < 64) acc += o; }
                int S0 = acc, S1 = S0 - (int)h0, S2 = S1 - (int)h1, S3 = S2 - (int)h2, S4 = S3 - (int)h3;
                if (lane == 0) { ctrl[0] = -1; ctrl[1] = 0; ctrl[2] = S0; }
                int bin = -1, ca = 0;
                if      (S0 >= KTARGET && S1 < KTARGET) { bin = 4 * lane;     ca = S1; }
                else if (S1 >= KTARGET && S2 < KTARGET) { bin = 4 * lane + 1; ca = S2; }
                else if (S2 >= KTARGET && S3 < KTARGET) { bin = 4 * lane + 2; ca = S3; }
                else if (S3 >= KTARGET && S4 < KTARGET) { bin = 4 * lane + 3; ca = S4; }
                if (bin >= 0) { ctrl[0] = bin; ctrl[1] = ca; }
            }
            __syncthreads();
            cumTotal = ctrl[2];
            if (cumTotal == 0) break;
            cumAbove = ctrl[1];
            const int B = ctrl[0];
            for (int j = tid; j < n; j += BLKC) {
                float sc = srow[(long)j * NCLS];
                if (sc > 0.05f) {
                    u64 ky = packkey(sc, j);
                    if (ky < UB) {
                        int bn = bin256(sc);
                        if (bn > B) { int sl = atomicAdd(&ctrl[4], 1); if (sl < KMAX) keysA[sl] = ky; }
                        else if (bn == B) {
                            int p = atomicAdd(&ctrl[3], 1);
                            int pos = KMAX - 1 - p;
                            if (pos >= cumAbove) keysA[pos] = ky;
                        }
                    }
                }
            }
            __syncthreads();
            const int cLo = ctrl[3], cHi = ctrl[4];
            const bool dropped = (cHi + cLo) > KMAX;
            trusted = dropped ? cHi : (cHi + cLo);
            if (trusted > 0) {
                if (tid < KMAX) e = keysA[tid];
                __syncthreads();
                sort512_1(e, tid, keysA, keysB);
            } else {
                u64 lb = 0;
                for (int j = tid; j < n; j += BLKC) {
                    float sc = srow[(long)j * NCLS];
                    if (sc > 0.05f) { u64 ky = packkey(sc, j); if (ky < UB && ky > lb) lb = ky; }
                }
                lb = wredmax64(lb);
                if (lane == 0) wl[wv] = lb;
                __syncthreads();
                if (tid == 0) { u64 bk = 0; for (int w = 0; w < 16; ++w) if (wl[w] > bk) bk = wl[w]; keysA[0] = bk; }
                trusted = 1;
                __syncthreads();
            }
        }

        // ---- preload ALL candidate boxes (one wide gather, off the per-chunk critical path) ----
        if (tid < KMAX) {
            u64 ky = (tid < trusted) ? keysA[tid] : 0;
            float4 bx = make_float4(0.f, 0.f, 0.f, 0.f);
            if (tid < trusted) bx = bb[(int)(~(u32)ky)];
            cbox[tid] = bx;
        }
        __syncthreads();

        // ---- greedy over sorted prefix: 2 barriers/chunk ----
        for (int base = 0; base < trusted; base += 64) {
            const int kcur = ctrl[5];        // uniform (after barrier)
            if (kcur >= MAXDET) break;
            const int ci = base + lane;
            const bool have = ci < trusted;
            const float4 pb = cbox[have ? ci : 0];
            const float par = (pb.z - pb.x) * (pb.w - pb.y);

            // (a) candidate vs prior accepted, split across 16 waves; float4 broadcast + exact f64 cmp
            bool sup = false;
            for (int a = wv; a < kcur; a += 16) {
                float4 ab = aBox[a];
                float am = (ab.z - ab.x) * (ab.w - ab.y);
                float ltx = fmaxf(ab.x, pb.x), lty = fmaxf(ab.y, pb.y);
                float rbx = fminf(ab.z, pb.z), rby = fminf(ab.w, pb.w);
                float wx = fmaxf(rbx - ltx, 0.0f), wy = fmaxf(rby - lty, 0.0f);
                float inter = wx * wy;
                float den = ((par + am) - inter) + 1e-9f;   // ref op order
                sup = sup || ((double)inter > T_MID * (double)den);
            }
            u64 bal = __ballot(sup && have);
            if (lane == 0 && bal) { atomicOr(&psupm[0], (u32)bal); atomicOr(&psupm[1], (u32)(bal >> 32)); }

            // (b) in-chunk kill matrix: killer=lane, victim m; 16 waves x 4 victims
#pragma unroll
            for (int r = 0; r < 4; ++r) {
                const int m = (r << 4) | wv;
                if (lane < m && (base + m) < trusted) {     // lane<m => lane has a real candidate
                    float4 vb = cbox[base + m];
                    float va = (vb.z - vb.x) * (vb.w - vb.y);
                    float ltx = fmaxf(pb.x, vb.x), lty = fmaxf(pb.y, vb.y);
                    float rbx = fminf(pb.z, vb.z), rby = fminf(pb.w, vb.w);
                    float wx = fmaxf(rbx - ltx, 0.0f), wy = fmaxf(rby - lty, 0.0f);
                    float inter = wx * wy;
                    float den = ((va + par) - inter) + 1e-9f;  // victim area first (ref order)
                    if ((double)inter > T_MID * (double)den) {
                        if (lane < 32) atomicOr(&kb0[m], 1u << lane);
                        else           atomicOr(&kb1[m], 1u << (lane - 32));
                    }
                }
            }
            __syncthreads();                 // bar 1

            // (c) wave 0: ballot fixpoint (== sequential greedy), accept, clear masks
            if (tid < 64) {
                const u64 kbm = ((u64)kb1[lane] << 32) | kb0[lane];
                const u64 ps  = ((u64)psupm[1] << 32) | psupm[0];
                const bool alive0 = have && !((ps >> lane) & 1);
                u64 accm = __ballot(alive0);
                for (int it = 0; it < 64; ++it) {
                    u64 nm = __ballot(alive0 && ((kbm & accm) == 0ull));
                    if (nm == accm) break;
                    accm = nm;
                }
                const bool a = (accm >> lane) & 1;
                const int rank = (int)__popcll(accm & ((1ull << lane) - 1ull));
                const int rem = MAXDET - kcur;
                if (a && rank < rem) {
                    const int slot = kcur + rank;
                    aBox[slot] = pb;
                    const u64 ky = keysA[ci];
                    selp[slot] = __uint_as_float((u32)(ky >> 32) ^ 0x80000000u);
                    idxp[slot] = (int)(~(u32)ky);
                }
                kb0[lane] = 0; kb1[lane] = 0;
                if (lane < 2) psupm[lane] = 0;
                if (lane == 0) {
                    const int cnt = (int)__popcll(accm);
                    ctrl[5] = kcur + (cnt < rem ? cnt : rem);
                }
            }
            __syncthreads();                 // bar 2
        }

        if (tid == 0) ubk = keysA[trusted - 1];
        first = false;
        __syncthreads();
        if (ctrl[5] >= MAXDET || cumTotal - trusted <= 0) break;
    }

    const int kfin = ctrl[5];
    for (int f = kfin + tid; f < MAXDET; f += BLKC) { selp[f] = NEGV; idxp[f] = 0; }
}

// ---------------- Kernel D: per-image global top-300 via 2-level select + gather (1024 thr) ----------------
#define OFF_B3D (NB * MAXDET * 4)
#define OFF_SC  (OFF_B3D + NB * MAXDET * 16)
#define OFF_LAB (OFF_SC + NB * MAXDET)

__global__ __launch_bounds__(1024, 1) void topk_kernel(
    const float4* __restrict__ boxes,
    const float*  __restrict__ b3d,
    const float*  __restrict__ sel_ws,
    const int*    __restrict__ idx_ws,
    float* __restrict__ out,
    int n)
{
    const int b = blockIdx.x;
    const int tid = threadIdx.x;
    const int lane = tid & 63;
    const int wv = tid >> 6;                  // 0..15
    const int M = NCLS * MAXDET;              // 6000

    __shared__ u64  kall[NCLS * MAXDET];      // 48KB
    __shared__ u32  h1[512];
    __shared__ u64  keysA[512], keysB[512];
    __shared__ int  wts[8], ews[8];
    __shared__ int  ctrl[8];
    __shared__ int  outA[MAXDET];

    const float* sp = sel_ws + b * M;
    for (int f = tid; f < M; f += 1024) {
        float v = sp[f];
        kall[f] = (v > 0.05f) ? packkey(v, f) : 0ull;
    }
    if (tid < 512) { h1[tid] = 0; keysA[tid] = 0; }
    if (tid > 0 && tid < 8) ctrl[tid] = 0;
    if (tid == 0) { ctrl[0] = -1; ctrl[5] = -1; }
    __syncthreads();

    for (int f = tid; f < M; f += 1024) {
        u64 k = kall[f];
        if (k) {
            float s = __uint_as_float((u32)(k >> 32) ^ 0x80000000u);
            atomicAdd(&h1[binfull(s) >> 9], 1u);
        }
    }
    __syncthreads();
    {
        const int h = (tid < 512) ? (int)h1[tid] : 0;
        int acc = h;
#pragma unroll
        for (int d = 1; d < 64; d <<= 1) { int o = __shfl_down(acc, d); if (lane + d < 64) acc += o; }
        if (lane == 0 && wv < 8) wts[wv] = acc;
        __syncthreads();
        if (tid < 8) { int e = 0; for (int w = tid + 1; w < 8; ++w) e += wts[w]; ews[tid] = e; }
        __syncthreads();
        if (tid < 512) {
            const int S = acc + ews[wv];
            if (S >= MAXDET && (S - h) < MAXDET) { ctrl[0] = tid; ctrl[1] = S - h; }
            if (tid == 0) ctrl[2] = S;
        }
    }
    __syncthreads();
    const int B1 = ctrl[0];
    const int cA1 = ctrl[1];

    if (tid < 512) h1[tid] = 0;
    __syncthreads();
    if (B1 >= 0) {
        for (int f = tid; f < M; f += 1024) {
            u64 k = kall[f];
            if (k) {
                float s = __uint_as_float((u32)(k >> 32) ^ 0x80000000u);
                int full = binfull(s);
                if ((full >> 9) == B1) atomicAdd(&h1[full & 511], 1u);
            }
        }
    }
    __syncthreads();
    const int KT2 = MAXDET - cA1;
    {
        const int h = (tid < 512) ? (int)h1[tid] : 0;
        int acc = h;
#pragma unroll
        for (int d = 1; d < 64; d <<= 1) { int o = __shfl_down(acc, d); if (lane + d < 64) acc += o; }
        if (lane == 0 && wv < 8) wts[wv] = acc;
        __syncthreads();
        if (tid < 8) { int e = 0; for (int w = tid + 1; w < 8; ++w) e += wts[w]; ews[tid] = e; }
        __syncthreads();
        if (tid < 512) {
            const int S = acc + ews[wv];
            if (B1 >= 0 && S >= KT2 && (S - h) < KT2) { ctrl[5] = tid; ctrl[6] = S - h; }
        }
    }
    __syncthreads();
    const int B2 = ctrl[5];
    const int cA2 = ctrl[6];

    for (int f = tid; f < M; f += 1024) {
        u64 k = kall[f];
        if (k) {
            float s = __uint_as_float((u32)(k >> 32) ^ 0x80000000u);
            int full = binfull(s);
            int bkt = full >> 9, sub = full & 511;
            bool hi = (B1 < 0) || (bkt > B1) || (bkt == B1 && sub > B2);
            bool lo = (B1 >= 0) && (bkt == B1) && (sub == B2);
            if (hi) { int slot = atomicAdd(&ctrl[3], 1); if (slot < 512) keysA[slot] = k; }
            else if (lo) { int p = atomicAdd(&ctrl[4], 1); int pos = 511 - p; if (pos >= cA1 + cA2) keysA[pos] = k; }
        }
    }
    __syncthreads();
    const bool dropped = (ctrl[3] + ctrl[4]) > 512;

    if (!dropped) {
        u64 e = (tid < 512) ? keysA[tid] : 0;
        int parity = 0;
        for (int k2 = 2; k2 <= 512; k2 <<= 1) {
            for (int jj = k2 >> 1; jj > 0; jj >>= 1) {
                if (jj >= 64) {
                    u64* buf = parity ? keysB : keysA; parity ^= 1;
                    if (tid < 512) buf[tid] = e;
                    __syncthreads();
                    if (tid < 512) { u64 p = buf[tid ^ jj]; e = cmb(e, p, tid, jj, k2); }
                } else {
                    if (tid < 512) { u64 p = __shfl_xor(e, jj); e = cmb(e, p, tid, jj, k2); }
                }
            }
        }
        __syncthreads();
        if (tid < 512) keysA[tid] = e;
        __syncthreads();
    } else {
        if (tid < 64) {
            int pos = 0;
            for (int k = 0; k < MAXDET; ++k) {
                u64 key = 0;
                if (lane < NCLS && pos < MAXDET) key = kall[lane * MAXDET + pos];
                u64 r = wredmax64(key);
                if (r != 0) {
                    u64 bal = __ballot(key == r);
                    int w = __ffsll((long long)bal) - 1;
                    if (lane == w) pos++;
                }
                if (lane == 0) keysA[k] = r;
            }
        }
        __syncthreads();
    }

    for (int k = tid; k < MAXDET; k += 1024) {
        const u64 kk = keysA[k];
        const bool ok = kk != 0;
        const int flat = (int)(~(u32)kk);
        const float sc = __uint_as_float((u32)(kk >> 32) ^ 0x80000000u);
        const int a = ok ? idx_ws[b * M + flat] : -1;
        const int cc = flat / MAXDET;
        float4 bx = make_float4(-1.f, -1.f, -1.f, -1.f);
        if (ok) bx = boxes[(long)b * n + a];
        out[(long)b * MAXDET * 4 + k * 4 + 0] = bx.x;
        out[(long)b * MAXDET * 4 + k * 4 + 1] = bx.y;
        out[(long)b * MAXDET * 4 + k * 4 + 2] = bx.z;
        out[(long)b * MAXDET * 4 + k * 4 + 3] = bx.w;
        out[OFF_SC  + (long)b * MAXDET + k] = ok ? sc : -1.0f;
        out[OFF_LAB + (long)b * MAXDET + k] = ok ? (float)cc : -1.0f;
        outA[k] = a;
    }
    __syncthreads();
    for (int q = tid; q < MAXDET * 16; q += 1024) {
        const int k = q >> 4;
        const int a = outA[k];
        out[OFF_B3D + (long)b * MAXDET * 16 + q] = (a >= 0) ? b3d[((long)b * n + a) * 16 + (q & 15)] : -1.0f;
    }
}

extern "C" void kernel_launch(void* const* d_in, const int* in_sizes, int n_in,
                              void* d_out, int out_size, void* d_ws, size_t ws_size,
                              hipStream_t stream)
{
    const float* boxes = (const float*)d_in[0];   // [8, N, 4]
    const float* b3d   = (const float*)d_in[1];   // [8, N, 16]
    const float* cls   = (const float*)d_in[2];   // [8, N, 20]
    float* out = (float*)d_out;

    const int n = in_sizes[0] / (NB * 4);         // 49104
    const int NP = NB * NCLS;                     // 160

    const size_t sumB   = (size_t)NP * NBIN * sizeof(u32);                   // 160KB
    const size_t cntB   = (size_t)NP * CSTR * sizeof(u32);                   // 10KB each
    const size_t metaB  = (size_t)NP * sizeof(int4);                         // 2.5KB
    const size_t sliceB = (size_t)NB * NSLICE * NCLS * NBIN * sizeof(u32);   // 10.5MB
    const size_t keysB_ = (size_t)NP * KMAX * sizeof(u64);                   // 640KB
    const size_t selB   = (size_t)NP * MAXDET * sizeof(float);

    char* p = (char*)d_ws;
    u32*  hist_sum_g   = (u32*)p;          p += sumB;     // | contiguous zero region:
    u32*  cntHi        = (u32*)p;          p += cntB;     // | sum + cntHi + cntLo
    u32*  cntLo        = (u32*)p;          p += cntB;     // | = 46080 words
    int4* meta_g       = (int4*)p;         p += metaB;
    u32*  hist_slice_g = (u32*)p;          p += sliceB;
    u64*  keys_g       = (u64*)p;          p += keysB_;
    float* sel_ws      = (float*)p;        p += selB;
    int*   idx_ws      = (int*)p;          p += selB;

    if (ws_size >= (size_t)(p - (char*)d_ws)) {
        const int zwords = (int)((sumB + 2 * cntB) / sizeof(u32));
        hipLaunchKernelGGL(zero_kernel, dim3((zwords + 255) / 256), dim3(256), 0, stream,
                           hist_sum_g, zwords);
        hipLaunchKernelGGL(hist_kernel, dim3(NB * NSLICE), dim3(BLKN), 0, stream,
                           cls, hist_slice_g, hist_sum_g, n);
        hipLaunchKernelGGL(collect_kernel, dim3(NB * NSLICE), dim3(BLKN), 0, stream,
                           cls, hist_sum_g, hist_slice_g, keys_g, cntHi, cntLo, meta_g, n);
        hipLaunchKernelGGL((nms_final_kernel<true>), dim3(NP), dim3(BLKC), 0, stream,
                           (const float4*)boxes, cls, keys_g, meta_g, cntHi, cntLo,
                           sel_ws, idx_ws, n);
        hipLaunchKernelGGL(topk_kernel, dim3(NB), dim3(1024), 0, stream,
                           (const float4*)boxes, b3d, sel_ws, idx_ws, out, n);
    } else {
        float* sel2 = (float*)d_ws;
        int*   idx2 = (int*)((char*)d_ws + selB);
        hipLaunchKernelGGL((nms_final_kernel<false>), dim3(NP), dim3(BLKC), 0, stream,
                           (const float4*)boxes, cls, nullptr, nullptr, nullptr, nullptr,
                           sel2, idx2, n);
        hipLaunchKernelGGL(topk_kernel, dim3(NB), dim3(1024), 0, stream,
                           (const float4*)boxes, b3d, sel2, idx2, out, n);
    }
}

// Round 15
// 77.640 us; speedup vs baseline: 1.9916x; 1.2022x over previous
//
#include <hip/hip_runtime.h>

#define NCLS    20
#define NB      8
#define MAXDET  300
#define NEGV    (-1e9f)
#define NEGH    (-5e8f)
#define BLKN    512
#define BLKC    1024
#define KTARGET 896       // fallback-path window target
#define KMAX    1024
#define NBIN    256
#define NSLICE  64
#define SLSH    6
#define NSEG    8
#define SEGCAP  128
#define CSTR    16        // counter stride (u32) -> one 64B line per counter
// fixed first-pass score cut: E[count > T0] ~ 500 per (image,class) on U^2 scores.
// Exactness does NOT depend on this value: overflow/shortfall use the exact rescan fallback.
#define T0F     0.97974f

// exact: RN_f32(inter/den) > 0.5  <=>  (double)inter > T_MID * (double)den   (den>0)
#define T_MID   0x1.000001p-1

typedef unsigned long long u64;
typedef unsigned int u32;

__device__ __forceinline__ u64 packkey(float s, int j) {
    // valid scores are positive: bits^0x80000000 order-preserving; ~j -> lower idx wins
    return ((u64)(__float_as_uint(s) ^ 0x80000000u) << 32) | (u32)(~(u32)j);
}
__device__ __forceinline__ u64 wredmax64(u64 k) {
#pragma unroll
    for (int off = 32; off > 0; off >>= 1) {
        u64 o = __shfl_xor(k, off);
        if (o > k) k = o;
    }
    return k;
}
__device__ __forceinline__ int binfull(float s) {
    int full = (int)(s * 262144.0f);
    return full > 262143 ? 262143 : full;
}
__device__ __forceinline__ int bin256(float s) { return binfull(s) >> 10; }

// ---------------- Kernel Z: zero the segment counters ----------------
__global__ __launch_bounds__(256) void zero_kernel(u32* __restrict__ p, int nwords)
{
    int i = blockIdx.x * 256 + threadIdx.x;
    if (i < nwords) p[i] = 0;
}

// ---------------- Kernel B: single-pass collect with fixed threshold ----------------
__global__ __launch_bounds__(BLKN) void collect_kernel(
    const float* __restrict__ cls, u64* __restrict__ keys_g, u32* __restrict__ cnt_g, int n)
{
    const int b = blockIdx.x & 7;            // same-image blocks -> same XCD
    const int slice = blockIdx.x >> 3;       // 0..63
    const int seg = slice >> 3;              // 0..7
    const int tid = threadIdx.x;
    const int F4 = (n * NCLS) >> 2;
    const int s0 = (int)(((long)slice * F4) >> SLSH);
    const int s1 = (int)(((long)(slice + 1) * F4) >> SLSH);

    const float4* p4 = (const float4*)(cls + (long)b * n * NCLS);
    for (int q = s0 + tid; q < s1; q += BLKN) {
        float4 v = p4[q];
        int f = q << 2;
        float ss[4] = {v.x, v.y, v.z, v.w};
#pragma unroll
        for (int e = 0; e < 4; ++e) {
            float sc = ss[e];
            if (sc > T0F) {                  // strict >; all such also pass the 0.05 ref filter
                u32 fe = (u32)(f + e);
                u32 c = fe % NCLS;
                int row = (int)(fe / NCLS);
                const int pair = b * NCLS + (int)c;
                u32 slot = atomicAdd(&cnt_g[(pair * NSEG + seg) * CSTR], 1u);
                if (slot < SEGCAP)
                    keys_g[(long)pair * KMAX + (seg << 7) + slot] = packkey(sc, row);
            }
        }
    }
}

// ---------------- hybrid bitonic: 1024 u64, 1/thread, 1024 threads ----------------
__device__ __forceinline__ u64 cmb(u64 e, u64 p, int i, int jj, int k2) {
    bool up = ((i & k2) == 0);
    bool low = ((i & jj) == 0);
    return (up == low) ? (e > p ? e : p) : (e < p ? e : p);
}
__device__ __forceinline__ void sort1024_1(u64& e, int tid, u64* bufA, u64* bufB) {
    int parity = 0;
    for (int k2 = 2; k2 <= KMAX; k2 <<= 1) {
        for (int jj = k2 >> 1; jj > 0; jj >>= 1) {
            if (jj >= 64) {
                u64* buf = parity ? bufB : bufA; parity ^= 1;
                buf[tid] = e;
                __syncthreads();
                u64 p = buf[tid ^ jj];
                e = cmb(e, p, tid, jj, k2);
            } else {
                u64 p = __shfl_xor(e, jj);
                e = cmb(e, p, tid, jj, k2);
            }
        }
    }
    __syncthreads();
    bufA[tid] = e;                 // final sorted array -> bufA
    __syncthreads();
}

// ---------------- Kernel C: per-pair sort + greedy (reference-exact) ----------------
template<bool PRE>
__global__ __launch_bounds__(BLKC, 1) void nms_final_kernel(
    const float4* __restrict__ boxes,
    const float*  __restrict__ cls,
    const u64* __restrict__ keys_g,
    const u32* __restrict__ cnt_g,
    float* __restrict__ sel_ws, int* __restrict__ idx_ws, int n)
{
    const int b = blockIdx.x & 7;
    const int c = blockIdx.x >> 3;
    const int pair = b * NCLS + c;
    const int tid = threadIdx.x;
    const int lane = tid & 63;
    const int wv = tid >> 6;                 // 0..15

    const float4* bb = boxes + (long)b * n;
    const float* srow = cls + (long)b * n * NCLS + c;   // strided (fallback rounds only)
    float* selp = sel_ws + pair * MAXDET;
    int*   idxp = idx_ws + pair * MAXDET;

    __shared__ u64    keysA[KMAX], keysB[KMAX];   // 16KB
    __shared__ float4 cbox[KMAX];                 // 16KB
    __shared__ float4 aBox[MAXDET];               // 4.8KB
    __shared__ u32    hist256[NBIN];
    __shared__ u32    kb0[64], kb1[64], psupm[2];
    __shared__ u64    wl[16];
    __shared__ int    ctrl[8];   // 0:B 1:cumAbove 2:cumTotal 3:cntLo 4:cntHi 5:k
    __shared__ u64    ubk;

    // window metadata (uniform loads; my_cnt avoids runtime-indexed register array)
    int pre_tot = 0; bool pre_ok = false; int my_cnt = 0;
    if (PRE) {
        bool over = false;
#pragma unroll
        for (int s = 0; s < NSEG; ++s) {
            int cv = (int)cnt_g[(pair * NSEG + s) * CSTR];
            pre_tot += cv;
            over = over || (cv > SEGCAP);
        }
        pre_ok = (!over) && (pre_tot > 0);
        my_cnt = (int)cnt_g[(pair * NSEG + (tid >> 7)) * CSTR];
    }

    if (tid == 0) { ubk = ~0ull; ctrl[5] = 0; }
    if (tid < 64) { kb0[tid] = 0; kb1[tid] = 0; }
    if (tid < 2)  psupm[tid] = 0;
    bool first = true;
    __syncthreads();

    while (true) {
        const u64 UB = ubk;
        u64 e = 0;
        int trusted, cumTotal;

        if (PRE && first && pre_ok) {
            // ---- fixed-threshold window: complete top-window, gaps masked by counts ----
            cumTotal = 0x7fffffff;           // unknown remaining; loop exit on k>=MAXDET only
            trusted = pre_tot;
            if ((tid & (SEGCAP - 1)) < my_cnt) e = keys_g[(long)pair * KMAX + tid];
            sort1024_1(e, tid, keysA, keysB);
        } else {
            // ---- fallback rounds: full strided rescan (exact; also covers overflow/empty) ----
            if (tid < NBIN) hist256[tid] = 0;
            keysA[tid] = 0;
            if (tid > 0 && tid < 5) ctrl[tid] = 0;
            if (tid == 0) ctrl[0] = -1;
            __syncthreads();
            for (int j = tid; j < n; j += BLKC) {
                float sc = srow[(long)j * NCLS];
                if (sc > 0.05f) { u64 ky = packkey(sc, j); if (ky < UB) atomicAdd(&hist256[bin256(sc)], 1u); }
            }
            __syncthreads();
            if (wv == 0) {
                u32 h0 = hist256[4 * lane], h1 = hist256[4 * lane + 1],
                    h2 = hist256[4 * lane + 2], h3 = hist256[4 * lane + 3];
                int acc = (int)(h0 + h1 + h2 + h3);
#pragma unroll
                for (int d = 1; d < 64; d <<= 1) { int o = __shfl_down(acc, d); if (lane + d < 64) acc += o; }
                int S0 = acc, S1 = S0 - (int)h0, S2 = S1 - (int)h1, S3 = S2 - (int)h2, S4 = S3 - (int)h3;
                if (lane == 0) { ctrl[0] = -1; ctrl[1] = 0; ctrl[2] = S0; }
                int bin = -1, ca = 0;
                if      (S0 >= KTARGET && S1 < KTARGET) { bin = 4 * lane;     ca = S1; }
                else if (S1 >= KTARGET && S2 < KTARGET) { bin = 4 * lane + 1; ca = S2; }
                else if (S2 >= KTARGET && S3 < KTARGET) { bin = 4 * lane + 2; ca = S3; }
                else if (S3 >= KTARGET && S4 < KTARGET) { bin = 4 * lane + 3; ca = S4; }
                if (bin >= 0) { ctrl[0] = bin; ctrl[1] = ca; }
            }
            __syncthreads();
            cumTotal = ctrl[2];
            if (cumTotal == 0) break;
            const int cumAbove = ctrl[1];
            const int B = ctrl[0];
            for (int j = tid; j < n; j += BLKC) {
                float sc = srow[(long)j * NCLS];
                if (sc > 0.05f) {
                    u64 ky = packkey(sc, j);
                    if (ky < UB) {
                        int bn = bin256(sc);
                        if (bn > B) { int sl = atomicAdd(&ctrl[4], 1); if (sl < KMAX) keysA[sl] = ky; }
                        else if (bn == B) {
                            int p = atomicAdd(&ctrl[3], 1);
                            int pos = KMAX - 1 - p;
                            if (pos >= cumAbove) keysA[pos] = ky;
                        }
                    }
                }
            }
            __syncthreads();
            const int cLo = ctrl[3], cHi = ctrl[4];
            const bool dropped = (cHi + cLo) > KMAX;
            trusted = dropped ? cHi : (cHi + cLo);
            if (trusted > 0) {
                e = keysA[tid];
                __syncthreads();
                sort1024_1(e, tid, keysA, keysB);
            } else {
                // boundary overflow w/ empty hi region: single best key < UB (progress)
                u64 lb = 0;
                for (int j = tid; j < n; j += BLKC) {
                    float sc = srow[(long)j * NCLS];
                    if (sc > 0.05f) { u64 ky = packkey(sc, j); if (ky < UB && ky > lb) lb = ky; }
                }
                lb = wredmax64(lb);
                if (lane == 0) wl[wv] = lb;
                __syncthreads();
                if (tid == 0) { u64 bk = 0; for (int w = 0; w < 16; ++w) if (wl[w] > bk) bk = wl[w]; keysA[0] = bk; }
                trusted = 1;
                __syncthreads();
            }
        }

        // ---- preload ALL candidate boxes (one wide gather) ----
        {
            u64 ky = (tid < trusted) ? keysA[tid] : 0;
            float4 bx = make_float4(0.f, 0.f, 0.f, 0.f);
            if (tid < trusted) bx = bb[(int)(~(u32)ky)];
            cbox[tid] = bx;
        }
        __syncthreads();

        // ---- greedy over sorted prefix: 2 barriers/chunk ----
        for (int base = 0; base < trusted; base += 64) {
            const int kcur = ctrl[5];        // uniform (after barrier)
            if (kcur >= MAXDET) break;
            const int ci = base + lane;
            const bool have = ci < trusted;
            const float4 pb = cbox[have ? ci : 0];
            const float par = (pb.z - pb.x) * (pb.w - pb.y);

            // (a) candidate vs prior accepted, split across 16 waves; exact f64 cmp
            bool sup = false;
            for (int a = wv; a < kcur; a += 16) {
                float4 ab = aBox[a];
                float am = (ab.z - ab.x) * (ab.w - ab.y);
                float ltx = fmaxf(ab.x, pb.x), lty = fmaxf(ab.y, pb.y);
                float rbx = fminf(ab.z, pb.z), rby = fminf(ab.w, pb.w);
                float wx = fmaxf(rbx - ltx, 0.0f), wy = fmaxf(rby - lty, 0.0f);
                float inter = wx * wy;
                float den = ((par + am) - inter) + 1e-9f;   // ref op order
                sup = sup || ((double)inter > T_MID * (double)den);
            }
            u64 bal = __ballot(sup && have);
            if (lane == 0 && bal) { atomicOr(&psupm[0], (u32)bal); atomicOr(&psupm[1], (u32)(bal >> 32)); }

            // (b) in-chunk kill matrix: killer=lane, victim m; 16 waves x 4 victims
#pragma unroll
            for (int r = 0; r < 4; ++r) {
                const int m = (r << 4) | wv;
                if (lane < m && (base + m) < trusted) {
                    float4 vb = cbox[base + m];
                    float va = (vb.z - vb.x) * (vb.w - vb.y);
                    float ltx = fmaxf(pb.x, vb.x), lty = fmaxf(pb.y, vb.y);
                    float rbx = fminf(pb.z, vb.z), rby = fminf(pb.w, vb.w);
                    float wx = fmaxf(rbx - ltx, 0.0f), wy = fmaxf(rby - lty, 0.0f);
                    float inter = wx * wy;
                    float den = ((va + par) - inter) + 1e-9f;  // victim area first (ref order)
                    if ((double)inter > T_MID * (double)den) {
                        if (lane < 32) atomicOr(&kb0[m], 1u << lane);
                        else           atomicOr(&kb1[m], 1u << (lane - 32));
                    }
                }
            }
            __syncthreads();                 // bar 1

            // (c) wave 0: ballot fixpoint (== sequential greedy), accept, clear masks
            if (tid < 64) {
                const u64 kbm = ((u64)kb1[lane] << 32) | kb0[lane];
                const u64 ps  = ((u64)psupm[1] << 32) | psupm[0];
                const bool alive0 = have && !((ps >> lane) & 1);
                u64 accm = __ballot(alive0);
                for (int it = 0; it < 64; ++it) {
                    u64 nm = __ballot(alive0 && ((kbm & accm) == 0ull));
                    if (nm == accm) break;
                    accm = nm;
                }
                const bool a = (accm >> lane) & 1;
                const int rank = (int)__popcll(accm & ((1ull << lane) - 1ull));
                const int rem = MAXDET - kcur;
                if (a && rank < rem) {
                    const int slot = kcur + rank;
                    aBox[slot] = pb;
                    const u64 ky = keysA[ci];
                    selp[slot] = __uint_as_float((u32)(ky >> 32) ^ 0x80000000u);
                    idxp[slot] = (int)(~(u32)ky);
                }
                kb0[lane] = 0; kb1[lane] = 0;
                if (lane < 2) psupm[lane] = 0;
                if (lane == 0) {
                    const int cnt = (int)__popcll(accm);
                    ctrl[5] = kcur + (cnt < rem ? cnt : rem);
                }
            }
            __syncthreads();                 // bar 2
        }

        if (tid == 0) ubk = keysA[trusted - 1];
        first = false;
        __syncthreads();
        if (ctrl[5] >= MAXDET || cumTotal - trusted <= 0) break;
    }

    const int kfin = ctrl[5];
    for (int f = kfin + tid; f < MAXDET; f += BLKC) { selp[f] = NEGV; idxp[f] = 0; }
}

// ---------------- Kernel D: per-image global top-300 via 2-level select + gather ----------------
#define OFF_B3D (NB * MAXDET * 4)
#define OFF_SC  (OFF_B3D + NB * MAXDET * 16)
#define OFF_LAB (OFF_SC + NB * MAXDET)

__global__ __launch_bounds__(1024, 1) void topk_kernel(
    const float4* __restrict__ boxes,
    const float*  __restrict__ b3d,
    const float*  __restrict__ sel_ws,
    const int*    __restrict__ idx_ws,
    float* __restrict__ out,
    int n)
{
    const int b = blockIdx.x;
    const int tid = threadIdx.x;
    const int lane = tid & 63;
    const int wv = tid >> 6;                  // 0..15
    const int M = NCLS * MAXDET;              // 6000

    __shared__ u64  kall[NCLS * MAXDET];      // 48KB
    __shared__ u32  h1[512];
    __shared__ u64  keysA[512], keysB[512];
    __shared__ int  wts[8], ews[8];
    __shared__ int  ctrl[8];
    __shared__ int  outA[MAXDET];

    const float* sp = sel_ws + b * M;
    for (int f = tid; f < M; f += 1024) {
        float v = sp[f];
        kall[f] = (v > 0.05f) ? packkey(v, f) : 0ull;
    }
    if (tid < 512) { h1[tid] = 0; keysA[tid] = 0; }
    if (tid > 0 && tid < 8) ctrl[tid] = 0;
    if (tid == 0) { ctrl[0] = -1; ctrl[5] = -1; }
    __syncthreads();

    for (int f = tid; f < M; f += 1024) {
        u64 k = kall[f];
        if (k) {
            float s = __uint_as_float((u32)(k >> 32) ^ 0x80000000u);
            atomicAdd(&h1[binfull(s) >> 9], 1u);
        }
    }
    __syncthreads();
    {
        const int h = (tid < 512) ? (int)h1[tid] : 0;
        int acc = h;
#pragma unroll
        for (int d = 1; d < 64; d <<= 1) { int o = __shfl_down(acc, d); if (lane + d < 64) acc += o; }
        if (lane == 0 && wv < 8) wts[wv] = acc;
        __syncthreads();
        if (tid < 8) { int e = 0; for (int w = tid + 1; w < 8; ++w) e += wts[w]; ews[tid] = e; }
        __syncthreads();
        if (tid < 512) {
            const int S = acc + ews[wv];
            if (S >= MAXDET && (S - h) < MAXDET) { ctrl[0] = tid; ctrl[1] = S - h; }
            if (tid == 0) ctrl[2] = S;
        }
    }
    __syncthreads();
    const int B1 = ctrl[0];
    const int cA1 = ctrl[1];

    if (tid < 512) h1[tid] = 0;
    __syncthreads();
    if (B1 >= 0) {
        for (int f = tid; f < M; f += 1024) {
            u64 k = kall[f];
            if (k) {
                float s = __uint_as_float((u32)(k >> 32) ^ 0x80000000u);
                int full = binfull(s);
                if ((full >> 9) == B1) atomicAdd(&h1[full & 511], 1u);
            }
        }
    }
    __syncthreads();
    const int KT2 = MAXDET - cA1;
    {
        const int h = (tid < 512) ? (int)h1[tid] : 0;
        int acc = h;
#pragma unroll
        for (int d = 1; d < 64; d <<= 1) { int o = __shfl_down(acc, d); if (lane + d < 64) acc += o; }
        if (lane == 0 && wv < 8) wts[wv] = acc;
        __syncthreads();
        if (tid < 8) { int e = 0; for (int w = tid + 1; w < 8; ++w) e += wts[w]; ews[tid] = e; }
        __syncthreads();
        if (tid < 512) {
            const int S = acc + ews[wv];
            if (B1 >= 0 && S >= KT2 && (S - h) < KT2) { ctrl[5] = tid; ctrl[6] = S - h; }
        }
    }
    __syncthreads();
    const int B2 = ctrl[5];
    const int cA2 = ctrl[6];

    for (int f = tid; f < M; f += 1024) {
        u64 k = kall[f];
        if (k) {
            float s = __uint_as_float((u32)(k >> 32) ^ 0x80000000u);
            int full = binfull(s);
            int bkt = full >> 9, sub = full & 511;
            bool hi = (B1 < 0) || (bkt > B1) || (bkt == B1 && sub > B2);
            bool lo = (B1 >= 0) && (bkt == B1) && (sub == B2);
            if (hi) { int slot = atomicAdd(&ctrl[3], 1); if (slot < 512) keysA[slot] = k; }
            else if (lo) { int p = atomicAdd(&ctrl[4], 1); int pos = 511 - p; if (pos >= cA1 + cA2) keysA[pos] = k; }
        }
    }
    __syncthreads();
    const bool dropped = (ctrl[3] + ctrl[4]) > 512;

    if (!dropped) {
        u64 e = (tid < 512) ? keysA[tid] : 0;
        int parity = 0;
        for (int k2 = 2; k2 <= 512; k2 <<= 1) {
            for (int jj = k2 >> 1; jj > 0; jj >>= 1) {
                if (jj >= 64) {
                    u64* buf = parity ? keysB : keysA; parity ^= 1;
                    if (tid < 512) buf[tid] = e;
                    __syncthreads();
                    if (tid < 512) { u64 p = buf[tid ^ jj]; e = cmb(e, p, tid, jj, k2); }
                } else {
                    if (tid < 512) { u64 p = __shfl_xor(e, jj); e = cmb(e, p, tid, jj, k2); }
                }
            }
        }
        __syncthreads();
        if (tid < 512) keysA[tid] = e;
        __syncthreads();
    } else {
        if (tid < 64) {
            int pos = 0;
            for (int k = 0; k < MAXDET; ++k) {
                u64 key = 0;
                if (lane < NCLS && pos < MAXDET) key = kall[lane * MAXDET + pos];
                u64 r = wredmax64(key);
                if (r != 0) {
                    u64 bal = __ballot(key == r);
                    int w = __ffsll((long long)bal) - 1;
                    if (lane == w) pos++;
                }
                if (lane == 0) keysA[k] = r;
            }
        }
        __syncthreads();
    }

    for (int k = tid; k < MAXDET; k += 1024) {
        const u64 kk = keysA[k];
        const bool ok = kk != 0;
        const int flat = (int)(~(u32)kk);
        const float sc = __uint_as_float((u32)(kk >> 32) ^ 0x80000000u);
        const int a = ok ? idx_ws[b * M + flat] : -1;
        const int cc = flat / MAXDET;
        float4 bx = make_float4(-1.f, -1.f, -1.f, -1.f);
        if (ok) bx = boxes[(long)b * n + a];
        out[(long)b * MAXDET * 4 + k * 4 + 0] = bx.x;
        out[(long)b * MAXDET * 4 + k * 4 + 1] = bx.y;
        out[(long)b * MAXDET * 4 + k * 4 + 2] = bx.z;
        out[(long)b * MAXDET * 4 + k * 4 + 3] = bx.w;
        out[OFF_SC  + (long)b * MAXDET + k] = ok ? sc : -1.0f;
        out[OFF_LAB + (long)b * MAXDET + k] = ok ? (float)cc : -1.0f;
        outA[k] = a;
    }
    __syncthreads();
    for (int q = tid; q < MAXDET * 16; q += 1024) {
        const int k = q >> 4;
        const int a = outA[k];
        out[OFF_B3D + (long)b * MAXDET * 16 + q] = (a >= 0) ? b3d[((long)b * n + a) * 16 + (q & 15)] : -1.0f;
    }
}

extern "C" void kernel_launch(void* const* d_in, const int* in_sizes, int n_in,
                              void* d_out, int out_size, void* d_ws, size_t ws_size,
                              hipStream_t stream)
{
    const float* boxes = (const float*)d_in[0];   // [8, N, 4]
    const float* b3d   = (const float*)d_in[1];   // [8, N, 16]
    const float* cls   = (const float*)d_in[2];   // [8, N, 20]
    float* out = (float*)d_out;

    const int n = in_sizes[0] / (NB * 4);         // 49104
    const int NP = NB * NCLS;                     // 160

    const size_t cntB   = (size_t)NP * NSEG * CSTR * sizeof(u32);            // 80KB
    const size_t keysB_ = (size_t)NP * KMAX * sizeof(u64);                   // 1.25MB
    const size_t selB   = (size_t)NP * MAXDET * sizeof(float);

    char* p = (char*)d_ws;
    u32*  cnt_g  = (u32*)p;                p += cntB;
    u64*  keys_g = (u64*)p;                p += keysB_;
    float* sel_ws = (float*)p;             p += selB;
    int*   idx_ws = (int*)p;               p += selB;

    if (ws_size >= (size_t)(p - (char*)d_ws)) {
        const int zwords = (int)(cntB / sizeof(u32));
        hipLaunchKernelGGL(zero_kernel, dim3((zwords + 255) / 256), dim3(256), 0, stream,
                           cnt_g, zwords);
        hipLaunchKernelGGL(collect_kernel, dim3(NB * NSLICE), dim3(BLKN), 0, stream,
                           cls, keys_g, cnt_g, n);
        hipLaunchKernelGGL((nms_final_kernel<true>), dim3(NP), dim3(BLKC), 0, stream,
                           (const float4*)boxes, cls, keys_g, cnt_g, sel_ws, idx_ws, n);
        hipLaunchKernelGGL(topk_kernel, dim3(NB), dim3(1024), 0, stream,
                           (const float4*)boxes, b3d, sel_ws, idx_ws, out, n);
    } else {
        float* sel2 = (float*)d_ws;
        int*   idx2 = (int*)((char*)d_ws + selB);
        hipLaunchKernelGGL((nms_final_kernel<false>), dim3(NP), dim3(BLKC), 0, stream,
                           (const float4*)boxes, cls, nullptr, nullptr, sel2, idx2, n);
        hipLaunchKernelGGL(topk_kernel, dim3(NB), dim3(1024), 0, stream,
                           (const float4*)boxes, b3d, sel2, idx2, out, n);
    }
}

// Round 16
// 75.215 us; speedup vs baseline: 2.0558x; 1.0322x over previous
//
#include <hip/hip_runtime.h>

#define NCLS    20
#define NB      8
#define MAXDET  300
#define NEGV    (-1e9f)
#define NEGH    (-5e8f)
#define BLKN    512
#define BLKC    1024
#define KTARGET 896       // fallback-path window target
#define KMAX    1024
#define NBIN    256
#define NSLICE  64
#define SLSH    6
#define NSEG    8
#define SEGCAP  128
#define CSTR    16        // counter stride (u32) -> one 64B line per counter
// fixed first-pass score cut: E[count > T0] ~ 430 per (image,class) on U^2 scores.
// Exactness does NOT depend on this value: overflow/shortfall use the exact rescan fallback.
#define T0F     0.98257f

// exact: RN_f32(inter/den) > 0.5  <=>  (double)inter > T_MID * (double)den   (den>0)
#define T_MID   0x1.000001p-1

typedef unsigned long long u64;
typedef unsigned int u32;

__device__ __forceinline__ u64 packkey(float s, int j) {
    // valid scores are positive: bits^0x80000000 order-preserving; ~j -> lower idx wins
    return ((u64)(__float_as_uint(s) ^ 0x80000000u) << 32) | (u32)(~(u32)j);
}
__device__ __forceinline__ u64 wredmax64(u64 k) {
#pragma unroll
    for (int off = 32; off > 0; off >>= 1) {
        u64 o = __shfl_xor(k, off);
        if (o > k) k = o;
    }
    return k;
}
__device__ __forceinline__ int binfull(float s) {
    int full = (int)(s * 262144.0f);
    return full > 262143 ? 262143 : full;
}
__device__ __forceinline__ int bin256(float s) { return binfull(s) >> 10; }

// ---------------- Kernel Z: zero the segment counters ----------------
__global__ __launch_bounds__(256) void zero_kernel(u32* __restrict__ p, int nwords)
{
    int i = blockIdx.x * 256 + threadIdx.x;
    if (i < nwords) p[i] = 0;
}

// ---------------- Kernel B: single-pass collect with fixed threshold ----------------
__global__ __launch_bounds__(BLKN) void collect_kernel(
    const float* __restrict__ cls, u64* __restrict__ keys_g, u32* __restrict__ cnt_g, int n)
{
    const int b = blockIdx.x & 7;            // same-image blocks -> same XCD
    const int slice = blockIdx.x >> 3;       // 0..63
    const int seg = slice >> 3;              // 0..7
    const int tid = threadIdx.x;
    const int F4 = (n * NCLS) >> 2;
    const int s0 = (int)(((long)slice * F4) >> SLSH);
    const int s1 = (int)(((long)(slice + 1) * F4) >> SLSH);

    const float4* p4 = (const float4*)(cls + (long)b * n * NCLS);
    for (int q = s0 + tid; q < s1; q += BLKN) {
        float4 v = p4[q];
        int f = q << 2;
        float ss[4] = {v.x, v.y, v.z, v.w};
#pragma unroll
        for (int e = 0; e < 4; ++e) {
            float sc = ss[e];
            if (sc > T0F) {                  // strict >; all such also pass the 0.05 ref filter
                u32 fe = (u32)(f + e);
                u32 c = fe % NCLS;
                int row = (int)(fe / NCLS);
                const int pair = b * NCLS + (int)c;
                u32 slot = atomicAdd(&cnt_g[(pair * NSEG + seg) * CSTR], 1u);
                if (slot < SEGCAP)
                    keys_g[(long)pair * KMAX + (seg << 7) + slot] = packkey(sc, row);
            }
        }
    }
}

// ---------------- hybrid bitonic helpers ----------------
__device__ __forceinline__ u64 cmb(u64 e, u64 p, int i, int jj, int k2) {
    bool up = ((i & k2) == 0);
    bool low = ((i & jj) == 0);
    return (up == low) ? (e > p ? e : p) : (e < p ? e : p);
}
// 1024 u64, 1/thread, 1024 threads
__device__ __forceinline__ void sort1024_1(u64& e, int tid, u64* bufA, u64* bufB) {
    int parity = 0;
    for (int k2 = 2; k2 <= 1024; k2 <<= 1) {
        for (int jj = k2 >> 1; jj > 0; jj >>= 1) {
            if (jj >= 64) {
                u64* buf = parity ? bufB : bufA; parity ^= 1;
                buf[tid] = e;
                __syncthreads();
                u64 p = buf[tid ^ jj];
                e = cmb(e, p, tid, jj, k2);
            } else {
                u64 p = __shfl_xor(e, jj);
                e = cmb(e, p, tid, jj, k2);
            }
        }
    }
    __syncthreads();
    bufA[tid] = e;                 // final sorted array -> bufA
    __syncthreads();
}
// 512 u64, tid<512 active (block may be 1024 wide)
__device__ __forceinline__ void sort512_1(u64& e, int tid, u64* bufA, u64* bufB) {
    int parity = 0;
    for (int k2 = 2; k2 <= 512; k2 <<= 1) {
        for (int jj = k2 >> 1; jj > 0; jj >>= 1) {
            if (jj >= 64) {
                u64* buf = parity ? bufB : bufA; parity ^= 1;
                if (tid < 512) buf[tid] = e;
                __syncthreads();
                if (tid < 512) { u64 p = buf[tid ^ jj]; e = cmb(e, p, tid, jj, k2); }
            } else {
                if (tid < 512) { u64 p = __shfl_xor(e, jj); e = cmb(e, p, tid, jj, k2); }
            }
        }
    }
    __syncthreads();
    if (tid < 512) bufA[tid] = e;
    __syncthreads();
}

// ---------------- Kernel C: per-pair compact + adaptive sort + greedy (reference-exact) ----------------
template<bool PRE>
__global__ __launch_bounds__(BLKC, 1) void nms_final_kernel(
    const float4* __restrict__ boxes,
    const float*  __restrict__ cls,
    const u64* __restrict__ keys_g,
    const u32* __restrict__ cnt_g,
    float* __restrict__ sel_ws, int* __restrict__ idx_ws, int n)
{
    const int b = blockIdx.x & 7;
    const int c = blockIdx.x >> 3;
    const int pair = b * NCLS + c;
    const int tid = threadIdx.x;
    const int lane = tid & 63;
    const int wv = tid >> 6;                 // 0..15

    const float4* bb = boxes + (long)b * n;
    const float* srow = cls + (long)b * n * NCLS + c;   // strided (fallback rounds only)
    float* selp = sel_ws + pair * MAXDET;
    int*   idxp = idx_ws + pair * MAXDET;

    __shared__ u64    keysA[KMAX], keysB[KMAX];   // 16KB
    __shared__ float4 cbox[KMAX];                 // 16KB
    __shared__ float4 aBox[MAXDET];               // 4.8KB
    __shared__ u32    hist256[NBIN];
    __shared__ u32    segc[NSEG];
    __shared__ u32    kb0[64], kb1[64], psupm[2];
    __shared__ u64    wl[16];
    __shared__ int    ctrl[8];   // 0:B 1:cumAbove 2:cumTotal 3:cntLo 4:cntHi 5:k
    __shared__ u64    ubk;

    if (PRE && tid < NSEG) segc[tid] = cnt_g[(pair * NSEG + tid) * CSTR];
    if (tid == 0) { ubk = ~0ull; ctrl[5] = 0; }
    if (tid < 64) { kb0[tid] = 0; kb1[tid] = 0; }
    if (tid < 2)  psupm[tid] = 0;
    bool first = true;
    __syncthreads();

    int pre_tot = 0; bool pre_ok = false;
    if (PRE) {
        bool over = false;
#pragma unroll
        for (int s = 0; s < NSEG; ++s) {
            int cv = (int)segc[s];
            pre_tot += cv;
            over = over || (cv > SEGCAP);
        }
        pre_ok = (!over) && (pre_tot > 0);
    }

    while (true) {
        const u64 UB = ubk;
        int trusted, cumTotal;

        if (PRE && first && pre_ok) {
            // ---- fixed-threshold window: scatter-compact, then adaptive sort ----
            cumTotal = 0x7fffffff;           // unknown remaining; exit on k>=MAXDET or next-round path
            trusted = pre_tot;
            keysA[tid] = 0;
            __syncthreads();
            {
                const int s = tid >> 7, r = tid & (SEGCAP - 1);
                if (r < (int)segc[s]) {
                    int start = 0;
#pragma unroll
                    for (int q = 0; q < NSEG; ++q) if (q < s) start += (int)segc[q];
                    keysA[start + r] = keys_g[(long)pair * KMAX + tid];
                }
            }
            __syncthreads();
            if (pre_tot <= 512) {
                u64 e = (tid < 512) ? keysA[tid] : 0;
                sort512_1(e, tid, keysA, keysB);
            } else {
                u64 e = keysA[tid];
                sort1024_1(e, tid, keysA, keysB);
            }
        } else {
            // ---- fallback rounds: full strided rescan (exact; covers overflow/empty/shortfall) ----
            if (tid < NBIN) hist256[tid] = 0;
            keysA[tid] = 0;
            if (tid > 0 && tid < 5) ctrl[tid] = 0;
            if (tid == 0) ctrl[0] = -1;
            __syncthreads();
            for (int j = tid; j < n; j += BLKC) {
                float sc = srow[(long)j * NCLS];
                if (sc > 0.05f) { u64 ky = packkey(sc, j); if (ky < UB) atomicAdd(&hist256[bin256(sc)], 1u); }
            }
            __syncthreads();
            if (wv == 0) {
                u32 h0 = hist256[4 * lane], h1 = hist256[4 * lane + 1],
                    h2 = hist256[4 * lane + 2], h3 = hist256[4 * lane + 3];
                int acc = (int)(h0 + h1 + h2 + h3);
#pragma unroll
                for (int d = 1; d < 64; d <<= 1) { int o = __shfl_down(acc, d); if (lane + d < 64) acc += o; }
                int S0 = acc, S1 = S0 - (int)h0, S2 = S1 - (int)h1, S3 = S2 - (int)h2, S4 = S3 - (int)h3;
                if (lane == 0) { ctrl[0] = -1; ctrl[1] = 0; ctrl[2] = S0; }
                int bin = -1, ca = 0;
                if      (S0 >= KTARGET && S1 < KTARGET) { bin = 4 * lane;     ca = S1; }
                else if (S1 >= KTARGET && S2 < KTARGET) { bin = 4 * lane + 1; ca = S2; }
                else if (S2 >= KTARGET && S3 < KTARGET) { bin = 4 * lane + 2; ca = S3; }
                else if (S3 >= KTARGET && S4 < KTARGET) { bin = 4 * lane + 3; ca = S4; }
                if (bin >= 0) { ctrl[0] = bin; ctrl[1] = ca; }
            }
            __syncthreads();
            cumTotal = ctrl[2];
            if (cumTotal == 0) break;
            const int cumAbove = ctrl[1];
            const int B = ctrl[0];
            for (int j = tid; j < n; j += BLKC) {
                float sc = srow[(long)j * NCLS];
                if (sc > 0.05f) {
                    u64 ky = packkey(sc, j);
                    if (ky < UB) {
                        int bn = bin256(sc);
                        if (bn > B) { int sl = atomicAdd(&ctrl[4], 1); if (sl < KMAX) keysA[sl] = ky; }
                        else if (bn == B) {
                            int p = atomicAdd(&ctrl[3], 1);
                            int pos = KMAX - 1 - p;
                            if (pos >= cumAbove) keysA[pos] = ky;
                        }
                    }
                }
            }
            __syncthreads();
            const int cLo = ctrl[3], cHi = ctrl[4];
            const bool dropped = (cHi + cLo) > KMAX;
            trusted = dropped ? cHi : (cHi + cLo);
            if (trusted > 0) {
                u64 e = keysA[tid];
                __syncthreads();
                sort1024_1(e, tid, keysA, keysB);
            } else {
                // boundary overflow w/ empty hi region: single best key < UB (progress)
                u64 lb = 0;
                for (int j = tid; j < n; j += BLKC) {
                    float sc = srow[(long)j * NCLS];
                    if (sc > 0.05f) { u64 ky = packkey(sc, j); if (ky < UB && ky > lb) lb = ky; }
                }
                lb = wredmax64(lb);
                if (lane == 0) wl[wv] = lb;
                __syncthreads();
                if (tid == 0) { u64 bk = 0; for (int w = 0; w < 16; ++w) if (wl[w] > bk) bk = wl[w]; keysA[0] = bk; }
                trusted = 1;
                __syncthreads();
            }
        }

        // ---- preload ALL candidate boxes (one wide gather) ----
        {
            u64 ky = (tid < trusted) ? keysA[tid] : 0;
            float4 bx = make_float4(0.f, 0.f, 0.f, 0.f);
            if (tid < trusted) bx = bb[(int)(~(u32)ky)];
            cbox[tid] = bx;
        }
        __syncthreads();

        // ---- greedy over sorted prefix: 2 barriers/chunk ----
        for (int base = 0; base < trusted; base += 64) {
            const int kcur = ctrl[5];        // uniform (after barrier)
            if (kcur >= MAXDET) break;
            const int ci = base + lane;
            const bool have = ci < trusted;
            const float4 pb = cbox[have ? ci : 0];
            const float par = (pb.z - pb.x) * (pb.w - pb.y);

            // (a) candidate vs prior accepted, split across 16 waves; exact f64 cmp
            bool sup = false;
            for (int a = wv; a < kcur; a += 16) {
                float4 ab = aBox[a];
                float am = (ab.z - ab.x) * (ab.w - ab.y);
                float ltx = fmaxf(ab.x, pb.x), lty = fmaxf(ab.y, pb.y);
                float rbx = fminf(ab.z, pb.z), rby = fminf(ab.w, pb.w);
                float wx = fmaxf(rbx - ltx, 0.0f), wy = fmaxf(rby - lty, 0.0f);
                float inter = wx * wy;
                float den = ((par + am) - inter) + 1e-9f;   // ref op order
                sup = sup || ((double)inter > T_MID * (double)den);
            }
            u64 bal = __ballot(sup && have);
            if (lane == 0 && bal) { atomicOr(&psupm[0], (u32)bal); atomicOr(&psupm[1], (u32)(bal >> 32)); }

            // (b) in-chunk kill matrix: killer=lane, victim m; 16 waves x 4 victims
#pragma unroll
            for (int r = 0; r < 4; ++r) {
                const int m = (r << 4) | wv;
                if (lane < m && (base + m) < trusted) {
                    float4 vb = cbox[base + m];
                    float va = (vb.z - vb.x) * (vb.w - vb.y);
                    float ltx = fmaxf(pb.x, vb.x), lty = fmaxf(pb.y, vb.y);
                    float rbx = fminf(pb.z, vb.z), rby = fminf(pb.w, vb.w);
                    float wx = fmaxf(rbx - ltx, 0.0f), wy = fmaxf(rby - lty, 0.0f);
                    float inter = wx * wy;
                    float den = ((va + par) - inter) + 1e-9f;  // victim area first (ref order)
                    if ((double)inter > T_MID * (double)den) {
                        if (lane < 32) atomicOr(&kb0[m], 1u << lane);
                        else           atomicOr(&kb1[m], 1u << (lane - 32));
                    }
                }
            }
            __syncthreads();                 // bar 1

            // (c) wave 0: ballot fixpoint (== sequential greedy), accept, clear masks
            if (tid < 64) {
                const u64 kbm = ((u64)kb1[lane] << 32) | kb0[lane];
                const u64 ps  = ((u64)psupm[1] << 32) | psupm[0];
                const bool alive0 = have && !((ps >> lane) & 1);
                u64 accm = __ballot(alive0);
                for (int it = 0; it < 64; ++it) {
                    u64 nm = __ballot(alive0 && ((kbm & accm) == 0ull));
                    if (nm == accm) break;
                    accm = nm;
                }
                const bool a = (accm >> lane) & 1;
                const int rank = (int)__popcll(accm & ((1ull << lane) - 1ull));
                const int rem = MAXDET - kcur;
                if (a && rank < rem) {
                    const int slot = kcur + rank;
                    aBox[slot] = pb;
                    const u64 ky = keysA[ci];
                    selp[slot] = __uint_as_float((u32)(ky >> 32) ^ 0x80000000u);
                    idxp[slot] = (int)(~(u32)ky);
                }
                kb0[lane] = 0; kb1[lane] = 0;
                if (lane < 2) psupm[lane] = 0;
                if (lane == 0) {
                    const int cnt = (int)__popcll(accm);
                    ctrl[5] = kcur + (cnt < rem ? cnt : rem);
                }
            }
            __syncthreads();                 // bar 2
        }

        if (tid == 0) ubk = keysA[trusted - 1];
        first = false;
        __syncthreads();
        if (ctrl[5] >= MAXDET || cumTotal - trusted <= 0) break;
    }

    const int kfin = ctrl[5];
    for (int f = kfin + tid; f < MAXDET; f += BLKC) { selp[f] = NEGV; idxp[f] = 0; }
}

// ---------------- Kernel D: per-image global top-300 via 2-level select + gather ----------------
#define OFF_B3D (NB * MAXDET * 4)
#define OFF_SC  (OFF_B3D + NB * MAXDET * 16)
#define OFF_LAB (OFF_SC + NB * MAXDET)

__global__ __launch_bounds__(1024, 1) void topk_kernel(
    const float4* __restrict__ boxes,
    const float*  __restrict__ b3d,
    const float*  __restrict__ sel_ws,
    const int*    __restrict__ idx_ws,
    float* __restrict__ out,
    int n)
{
    const int b = blockIdx.x;
    const int tid = threadIdx.x;
    const int lane = tid & 63;
    const int wv = tid >> 6;                  // 0..15
    const int M = NCLS * MAXDET;              // 6000

    __shared__ u64  kall[NCLS * MAXDET];      // 48KB
    __shared__ u32  h1[512];
    __shared__ u64  keysA[512], keysB[512];
    __shared__ int  wts[8], ews[8];
    __shared__ int  ctrl[8];
    __shared__ int  outA[MAXDET];

    const float* sp = sel_ws + b * M;
    for (int f = tid; f < M; f += 1024) {
        float v = sp[f];
        kall[f] = (v > 0.05f) ? packkey(v, f) : 0ull;
    }
    if (tid < 512) { h1[tid] = 0; keysA[tid] = 0; }
    if (tid > 0 && tid < 8) ctrl[tid] = 0;
    if (tid == 0) { ctrl[0] = -1; ctrl[5] = -1; }
    __syncthreads();

    for (int f = tid; f < M; f += 1024) {
        u64 k = kall[f];
        if (k) {
            float s = __uint_as_float((u32)(k >> 32) ^ 0x80000000u);
            atomicAdd(&h1[binfull(s) >> 9], 1u);
        }
    }
    __syncthreads();
    {
        const int h = (tid < 512) ? (int)h1[tid] : 0;
        int acc = h;
#pragma unroll
        for (int d = 1; d < 64; d <<= 1) { int o = __shfl_down(acc, d); if (lane + d < 64) acc += o; }
        if (lane == 0 && wv < 8) wts[wv] = acc;
        __syncthreads();
        if (tid < 8) { int e = 0; for (int w = tid + 1; w < 8; ++w) e += wts[w]; ews[tid] = e; }
        __syncthreads();
        if (tid < 512) {
            const int S = acc + ews[wv];
            if (S >= MAXDET && (S - h) < MAXDET) { ctrl[0] = tid; ctrl[1] = S - h; }
            if (tid == 0) ctrl[2] = S;
        }
    }
    __syncthreads();
    const int B1 = ctrl[0];
    const int cA1 = ctrl[1];

    if (tid < 512) h1[tid] = 0;
    __syncthreads();
    if (B1 >= 0) {
        for (int f = tid; f < M; f += 1024) {
            u64 k = kall[f];
            if (k) {
                float s = __uint_as_float((u32)(k >> 32) ^ 0x80000000u);
                int full = binfull(s);
                if ((full >> 9) == B1) atomicAdd(&h1[full & 511], 1u);
            }
        }
    }
    __syncthreads();
    const int KT2 = MAXDET - cA1;
    {
        const int h = (tid < 512) ? (int)h1[tid] : 0;
        int acc = h;
#pragma unroll
        for (int d = 1; d < 64; d <<= 1) { int o = __shfl_down(acc, d); if (lane + d < 64) acc += o; }
        if (lane == 0 && wv < 8) wts[wv] = acc;
        __syncthreads();
        if (tid < 8) { int e = 0; for (int w = tid + 1; w < 8; ++w) e += wts[w]; ews[tid] = e; }
        __syncthreads();
        if (tid < 512) {
            const int S = acc + ews[wv];
            if (B1 >= 0 && S >= KT2 && (S - h) < KT2) { ctrl[5] = tid; ctrl[6] = S - h; }
        }
    }
    __syncthreads();
    const int B2 = ctrl[5];
    const int cA2 = ctrl[6];

    for (int f = tid; f < M; f += 1024) {
        u64 k = kall[f];
        if (k) {
            float s = __uint_as_float((u32)(k >> 32) ^ 0x80000000u);
            int full = binfull(s);
            int bkt = full >> 9, sub = full & 511;
            bool hi = (B1 < 0) || (bkt > B1) || (bkt == B1 && sub > B2);
            bool lo = (B1 >= 0) && (bkt == B1) && (sub == B2);
            if (hi) { int slot = atomicAdd(&ctrl[3], 1); if (slot < 512) keysA[slot] = k; }
            else if (lo) { int p = atomicAdd(&ctrl[4], 1); int pos = 511 - p; if (pos >= cA1 + cA2) keysA[pos] = k; }
        }
    }
    __syncthreads();
    const bool dropped = (ctrl[3] + ctrl[4]) > 512;

    if (!dropped) {
        u64 e = (tid < 512) ? keysA[tid] : 0;
        int parity = 0;
        for (int k2 = 2; k2 <= 512; k2 <<= 1) {
            for (int jj = k2 >> 1; jj > 0; jj >>= 1) {
                if (jj >= 64) {
                    u64* buf = parity ? keysB : keysA; parity ^= 1;
                    if (tid < 512) buf[tid] = e;
                    __syncthreads();
                    if (tid < 512) { u64 p = buf[tid ^ jj]; e = cmb(e, p, tid, jj, k2); }
                } else {
                    if (tid < 512) { u64 p = __shfl_xor(e, jj); e = cmb(e, p, tid, jj, k2); }
                }
            }
        }
        __syncthreads();
        if (tid < 512) keysA[tid] = e;
        __syncthreads();
    } else {
        if (tid < 64) {
            int pos = 0;
            for (int k = 0; k < MAXDET; ++k) {
                u64 key = 0;
                if (lane < NCLS && pos < MAXDET) key = kall[lane * MAXDET + pos];
                u64 r = wredmax64(key);
                if (r != 0) {
                    u64 bal = __ballot(key == r);
                    int w = __ffsll((long long)bal) - 1;
                    if (lane == w) pos++;
                }
                if (lane == 0) keysA[k] = r;
            }
        }
        __syncthreads();
    }

    for (int k = tid; k < MAXDET; k += 1024) {
        const u64 kk = keysA[k];
        const bool ok = kk != 0;
        const int flat = (int)(~(u32)kk);
        const float sc = __uint_as_float((u32)(kk >> 32) ^ 0x80000000u);
        const int a = ok ? idx_ws[b * M + flat] : -1;
        const int cc = flat / MAXDET;
        float4 bx = make_float4(-1.f, -1.f, -1.f, -1.f);
        if (ok) bx = boxes[(long)b * n + a];
        out[(long)b * MAXDET * 4 + k * 4 + 0] = bx.x;
        out[(long)b * MAXDET * 4 + k * 4 + 1] = bx.y;
        out[(long)b * MAXDET * 4 + k * 4 + 2] = bx.z;
        out[(long)b * MAXDET * 4 + k * 4 + 3] = bx.w;
        out[OFF_SC  + (long)b * MAXDET + k] = ok ? sc : -1.0f;
        out[OFF_LAB + (long)b * MAXDET + k] = ok ? (float)cc : -1.0f;
        outA[k] = a;
    }
    __syncthreads();
    for (int q = tid; q < MAXDET * 16; q += 1024) {
        const int k = q >> 4;
        const int a = outA[k];
        out[OFF_B3D + (long)b * MAXDET * 16 + q] = (a >= 0) ? b3d[((long)b * n + a) * 16 + (q & 15)] : -1.0f;
    }
}

extern "C" void kernel_launch(void* const* d_in, const int* in_sizes, int n_in,
                              void* d_out, int out_size, void* d_ws, size_t ws_size,
                              hipStream_t stream)
{
    const float* boxes = (const float*)d_in[0];   // [8, N, 4]
    const float* b3d   = (const float*)d_in[1];   // [8, N, 16]
    const float* cls   = (const float*)d_in[2];   // [8, N, 20]
    float* out = (float*)d_out;

    const int n = in_sizes[0] / (NB * 4);         // 49104
    const int NP = NB * NCLS;                     // 160

    const size_t cntB   = (size_t)NP * NSEG * CSTR * sizeof(u32);            // 80KB
    const size_t keysB_ = (size_t)NP * KMAX * sizeof(u64);                   // 1.25MB
    const size_t selB   = (size_t)NP * MAXDET * sizeof(float);

    char* p = (char*)d_ws;
    u32*  cnt_g  = (u32*)p;                p += cntB;
    u64*  keys_g = (u64*)p;                p += keysB_;
    float* sel_ws = (float*)p;             p += selB;
    int*   idx_ws = (int*)p;               p += selB;

    if (ws_size >= (size_t)(p - (char*)d_ws)) {
        const int zwords = (int)(cntB / sizeof(u32));
        hipLaunchKernelGGL(zero_kernel, dim3((zwords + 255) / 256), dim3(256), 0, stream,
                           cnt_g, zwords);
        hipLaunchKernelGGL(collect_kernel, dim3(NB * NSLICE), dim3(BLKN), 0, stream,
                           cls, keys_g, cnt_g, n);
        hipLaunchKernelGGL((nms_final_kernel<true>), dim3(NP), dim3(BLKC), 0, stream,
                           (const float4*)boxes, cls, keys_g, cnt_g, sel_ws, idx_ws, n);
        hipLaunchKernelGGL(topk_kernel, dim3(NB), dim3(1024), 0, stream,
                           (const float4*)boxes, b3d, sel_ws, idx_ws, out, n);
    } else {
        float* sel2 = (float*)d_ws;
        int*   idx2 = (int*)((char*)d_ws + selB);
        hipLaunchKernelGGL((nms_final_kernel<false>), dim3(NP), dim3(BLKC), 0, stream,
                           (const float4*)boxes, cls, nullptr, nullptr, sel2, idx2, n);
        hipLaunchKernelGGL(topk_kernel, dim3(NB), dim3(1024), 0, stream,
                           (const float4*)boxes, b3d, sel2, idx2, out, n);
    }
}